// Round 1
// baseline (5585.792 us; speedup 1.0000x reference)
//
#include <hip/hip_runtime.h>

// ---------------------------------------------------------------------------
// VehicleTrajectoryDecoder: B=32, N=256, D=512, H=8 (dh=64), T=60, DFF=2048.
// R10: no cross-batch coupling exists, so the 7 grid-wide barriers/step are
// replaced by 4 per-batch 8-block barriers/step (group b = bid&31, heads
// h = bid>>5 -> one XCD under round-robin dispatch). Wo-projection phases
// eliminated: each head-block computes the k-chunk-h PARTIAL of the full
// u1/ctx/u2 rows from its own attention output held in LDS and atomicAdds
// (same MACs/weight bytes as the old col-sliced phases). LNs are computed
// redundantly per block from the completed row (elementwise, cheap). x_next
// lives in LDS (xrow) -> no t->t+1 global round trip and no trailing
// barrier; ctx is double-buffered; u1/u2 re-zeroed >=1 barrier away from
// both reader and next writer. u3 is col-sliced (no atomics). All barriers
// are full-block (R8/R9 lesson); cross-block data via agent-scope ld/st.
// ---------------------------------------------------------------------------

#define NB 32
#define NN 256
#define DD 512
#define NH 8
#define DH 64
#define TT 60
#define DF 2048
#define NBLK 256
#define NTHR 512

typedef unsigned short ushort_t;

// ---- workspace layout ------------------------------------------------------
constexpr size_t SZ_KV  = (size_t)NB * NN * DD;   // 4194304
constexpr size_t SZ_ROW = (size_t)NB * DD;
constexpr size_t SZ_SAB = (size_t)NB * NH * TT * DH;
constexpr size_t OFF_KS32 = 0;
constexpr size_t OFF_VS32 = SZ_KV;
constexpr size_t OFF_KC32 = 2 * SZ_KV;
constexpr size_t OFF_VC32 = 3 * SZ_KV;
constexpr size_t OFF_X   = 0;
constexpr size_t OFF_CT1 = OFF_X   + SZ_ROW;
constexpr size_t OFF_U1  = OFF_CT1 + SZ_ROW;
constexpr size_t OFF_U2  = OFF_U1  + SZ_ROW;
constexpr size_t OFF_CT0 = OFF_U2  + SZ_ROW;
constexpr size_t OFF_U3  = OFF_CT0 + SZ_ROW;
constexpr size_t OFF_H   = OFF_U3  + SZ_ROW;     // NB*DF floats
constexpr size_t OFF_BF   = 4 * SZ_KV;
constexpr size_t UOFF_KST = 0;
constexpr size_t UOFF_KCT = SZ_KV;
constexpr size_t UOFF_VSH = 2 * SZ_KV;
constexpr size_t UOFF_VCH = 3 * SZ_KV;
constexpr size_t UOFF_KSA = 4 * SZ_KV;
constexpr size_t UOFF_VSA = UOFF_KSA + SZ_SAB;
constexpr size_t UOFF_W8  = UOFF_VSA + SZ_SAB;
constexpr size_t UOFF_W1  = UOFF_W8 + 8ull * DD * DD;
constexpr size_t UOFF_W2  = UOFF_W1 + (size_t)DD * DF;
constexpr size_t UEND     = UOFF_W2 + (size_t)DF * DD;
constexpr size_t OFF_FLG  = OFF_BF + (UEND + 1) / 2;

// ---- helpers ----------------------------------------------------------------
__device__ __forceinline__ float ldg_a(const float* p) {
  return __hip_atomic_load(p, __ATOMIC_RELAXED, __HIP_MEMORY_SCOPE_AGENT);
}
__device__ __forceinline__ void stg_a(float* p, float v) {
  __hip_atomic_store(p, v, __ATOMIC_RELAXED, __HIP_MEMORY_SCOPE_AGENT);
}
__device__ __forceinline__ float bf2f(ushort_t u) {
  return __uint_as_float(((unsigned)u) << 16);
}
__device__ __forceinline__ ushort_t f2bf(float f) {
  unsigned u = __float_as_uint(f);
  return (ushort_t)((u + 0x7FFFu + ((u >> 16) & 1u)) >> 16);
}

// ---- params ----------------------------------------------------------------
struct Params {
  const float *pe;
  const float *sa_bq, *sa_bk, *sa_bv, *s_bq, *sa_bo, *s_bo, *ca_bq, *ca_bo;
  const float *ln1w, *ln1b, *ln2w, *ln2b, *ln3w, *ln3b;
  const float *b1, *b2, *Wout, *bout;
  const ushort_t *w8, *w1b, *w2b;
  const ushort_t *KsT, *KcT, *VsH, *VcH;
  ushort_t *KsaB, *VsaB;
  float *xcur, *u1, *u2, *u3, *hbuf, *ctx0, *ctx1;
  float *out;
  unsigned *flags;
};

// ---- per-batch 8-block barrier (monotonic counter, 128B-spaced lines) ------
__device__ __forceinline__ void gbar(unsigned* cnt, int tid, unsigned& grnd) {
  __builtin_amdgcn_s_waitcnt(0);
  __syncthreads();
  grnd += NH;
  if (tid == 0) {
    __hip_atomic_fetch_add(cnt, 1u, __ATOMIC_RELAXED, __HIP_MEMORY_SCOPE_AGENT);
    while (__hip_atomic_load(cnt, __ATOMIC_RELAXED,
                             __HIP_MEMORY_SCOPE_AGENT) < grnd)
      __builtin_amdgcn_s_sleep(1);
  }
  __syncthreads();
}

// ---- persistent decode (256 blocks x 512 threads; 32 groups x 8 heads) -----
__global__ __launch_bounds__(512) void decode_persistent(Params P) {
  __shared__ __align__(16) float sX[2048];    // scratch
  __shared__ __align__(16) float sPart[512];
  __shared__ float sAux[64];
  __shared__ __align__(16) float xrow[512];   // persistent x (incl. pe)
  __shared__ __align__(16) float y1s[512];    // LN1 output row
  __shared__ __align__(16) float zs[512];     // LN2 output row
  int tid = threadIdx.x;
  int bid = blockIdx.x;
  int b = bid & 31, h = bid >> 5;             // group b on one XCD (heuristic)
  int idx8 = b * NH + h;                      // legacy (b,h) linear index
  unsigned* cnt = P.flags + b * 32;           // 128B apart
  unsigned grnd = 0;

  xrow[tid] = ldg_a(P.xcur + (size_t)b * DD + tid);
  __syncthreads();

  for (int t = 0; t < TT; t++) {
    // ==== Phase A: proj q/k/v/qs + self-attn + spatial + u1/ctx partials ====
    {
      // proj: wave w: matrix m=w>>1, k-half=w&1; lane c -> col h*64+c
      {
        int w = tid >> 6, c = tid & 63, m = w >> 1, half = w & 1;
        int col = h * DH + c;
        const ushort4* wp = (const ushort4*)(P.w8 + (size_t)m * DD * DD) + col;
        float acc = 0.f;
        #pragma unroll 8
        for (int kq = half * 64; kq < half * 64 + 64; kq++) {
          ushort4 wv = wp[(size_t)kq * DD];
          float4 xv = *(const float4*)(xrow + kq * 4);
          acc += xv.x * bf2f(wv.x) + xv.y * bf2f(wv.y) +
                 xv.z * bf2f(wv.z) + xv.w * bf2f(wv.w);
        }
        sPart[tid] = acc;
      }
      __syncthreads();
      if (tid < 256) {  // combine halves + bias; stash in sX[512..768)
        int m = tid >> 6, c = tid & 63, col = h * DH + c;
        const float* bias = (m == 0) ? P.sa_bq : (m == 1) ? P.sa_bk
                          : (m == 2) ? P.sa_bv : P.s_bq;
        float val = sPart[(2 * m) * 64 + c] + sPart[(2 * m + 1) * 64 + c]
                    + bias[col];
        sX[512 + tid] = val;
        if (m == 1) P.KsaB[((size_t)idx8 * TT + t) * DH + c] = f2bf(val);
        if (m == 2) P.VsaB[((size_t)idx8 * TT + t) * DH + c] = f2bf(val);
      }
      __syncthreads();

      // ---- self-attn over L keys (head-private bf16 cache) ----
      int L = t + 1;
      float* sQ  = sX + 512;        // q_self [64]
      float* sQs = sX + 704;        // q_spatial [64]
      float* sPb = sX + 768;        // self probs [64]
      float* sB  = sX + 1024;       // partials [512]
      if (tid < 64) {
        float sc = -1e30f;
        if (tid < L) {
          const ushort_t* kp = P.KsaB + ((size_t)idx8 * TT + tid) * DH;
          float a = 0.f;
          #pragma unroll
          for (int i = 0; i < DH; i += 4) {
            ushort4 kv = *(const ushort4*)(kp + i);
            a += sQ[i] * bf2f(kv.x) + sQ[i + 1] * bf2f(kv.y) +
                 sQ[i + 2] * bf2f(kv.z) + sQ[i + 3] * bf2f(kv.w);
          }
          sc = a * 0.125f;
        }
        float mx = sc;
        #pragma unroll
        for (int s = 32; s >= 1; s >>= 1) mx = fmaxf(mx, __shfl_xor(mx, s));
        float e = (tid < L) ? __expf(sc - mx) : 0.f;
        float s2 = e;
        #pragma unroll
        for (int s = 32; s >= 1; s >>= 1) s2 += __shfl_xor(s2, s);
        sPb[tid] = e;
        if (tid == 0) sAux[12] = 1.f / s2;
      }
      __syncthreads();
      {  // PV: 8 key-groups x 64 d
        int g = tid >> 6, d = tid & 63;
        float a2 = 0.f;
        for (int j = g; j < L; j += 8)
          a2 += sPb[j] * bf2f(P.VsaB[((size_t)idx8 * TT + j) * DH + d]);
        sB[tid] = a2;
      }
      __syncthreads();
      if (tid < 64) {   // aSA head-slice -> sX[0..64)
        float o = 0.f;
        #pragma unroll
        for (int i = 0; i < 8; i++) o += sB[i * 64 + tid];
        sX[tid] = o * sAux[12];
      }
      __syncthreads();

      // ---- spatial attn over 256 keys (d-split scores, 8-way PV) ----
      {
        int n = tid & 255, dh2 = tid >> 8;
        const ushort_t* kp = P.KsT + ((size_t)b * DD + h * DH) * NN + n;
        float a = 0.f;
        #pragma unroll 8
        for (int i = dh2 * 32; i < dh2 * 32 + 32; i++)
          a += sQs[i] * bf2f(kp[(size_t)i * NN]);
        sPart[tid] = a;
      }
      __syncthreads();
      float* sPr = sX + 1536;  // spatial probs [256]
      if (tid < 256) {  // softmax stage 1 (full-block sync'd)
        float sc = (sPart[tid] + sPart[256 + tid]) * 0.125f;
        sPr[tid] = sc;
        int w = tid >> 6, lane = tid & 63;
        float mx = sc;
        #pragma unroll
        for (int s = 32; s >= 1; s >>= 1) mx = fmaxf(mx, __shfl_xor(mx, s));
        if (lane == 0) sAux[w] = mx;
      }
      __syncthreads();
      if (tid < 256) {  // softmax stage 2
        int w = tid >> 6, lane = tid & 63;
        float mx = fmaxf(fmaxf(sAux[0], sAux[1]), fmaxf(sAux[2], sAux[3]));
        float e = __expf(sPr[tid] - mx);
        sPr[tid] = e;
        float s2 = e;
        #pragma unroll
        for (int s = 32; s >= 1; s >>= 1) s2 += __shfl_xor(s2, s);
        if (lane == 0) sAux[4 + w] = s2;
      }
      __syncthreads();
      {
        int g = tid >> 6, d = tid & 63;
        float inv = 1.f / (sAux[4] + sAux[5] + sAux[6] + sAux[7]);
        const ushort_t* vp = P.VsH + ((size_t)idx8 * NN + g * 32) * DH + d;
        float acc = 0.f;
        #pragma unroll 4
        for (int n = 0; n < 32; n++) acc += sPr[g * 32 + n] * bf2f(vp[(size_t)n * DH]);
        sB[tid] = acc * inv;
      }
      __syncthreads();
      if (tid < 64) {   // aSP head-slice -> sX[64..128)
        float o = 0.f;
        #pragma unroll
        for (int i = 0; i < 8; i++) o += sB[i * 64 + tid];
        sX[64 + tid] = o;
      }
      __syncthreads();

      // ---- u1/ctx k-chunk-h partials: row-slice gemv + atomicAdd ----
      {
        float* ctxp = (t & 1) ? P.ctx1 : P.ctx0;
        const ushort4* wpa = (const ushort4*)(P.w8 + 4ull * DD * DD) + tid;
        const ushort4* wpb = (const ushort4*)(P.w8 + 5ull * DD * DD) + tid;
        float acc1 = (h == 0) ? P.sa_bo[tid] + xrow[tid] : 0.f;
        float acc2 = (h == 0) ? P.s_bo[tid] : 0.f;
        #pragma unroll 8
        for (int j = 0; j < 16; j++) {
          int k4 = h * 16 + j;
          ushort4 wv = wpa[(size_t)k4 * DD];
          float4 xv = *(const float4*)(sX + j * 4);
          acc1 += xv.x * bf2f(wv.x) + xv.y * bf2f(wv.y) +
                  xv.z * bf2f(wv.z) + xv.w * bf2f(wv.w);
          ushort4 wv2 = wpb[(size_t)k4 * DD];
          float4 xv2 = *(const float4*)(sX + 64 + j * 4);
          acc2 += xv2.x * bf2f(wv2.x) + xv2.y * bf2f(wv2.y) +
                  xv2.z * bf2f(wv2.z) + xv2.w * bf2f(wv2.w);
        }
        atomicAdd(&P.u1[(size_t)b * DD + tid], acc1);
        atomicAdd(&ctxp[(size_t)b * DD + tid], acc2);
      }
    }
    gbar(cnt, tid, grnd);

    // ==== Phase B: LN1(u1) -> y1s ; qc ; cross-attn ; u2 partial ============
    {
      float u = ldg_a(P.u1 + (size_t)b * DD + tid);
      {
        int w = tid >> 6, lane = tid & 63;
        float s = u, q2 = u * u;
        #pragma unroll
        for (int m = 32; m >= 1; m >>= 1) { s += __shfl_xor(s, m); q2 += __shfl_xor(q2, m); }
        if (lane == 0) { sAux[w] = s; sAux[8 + w] = q2; }
      }
      __syncthreads();
      {
        float ss = 0.f, qq = 0.f;
        #pragma unroll
        for (int i = 0; i < 8; i++) { ss += sAux[i]; qq += sAux[8 + i]; }
        float mean = ss * (1.f / 512.f);
        float inv = rsqrtf(qq * (1.f / 512.f) - mean * mean + 1e-5f);
        y1s[tid] = (u - mean) * inv * P.ln1w[tid] + P.ln1b[tid];
      }
      __syncthreads();
      {  // qc: 8 k-chunks of 64
        int c = tid & 63, w = tid >> 6, col = h * DH + c;
        const ushort4* wp = (const ushort4*)(P.w8 + 6ull * DD * DD) + col;
        float acc = 0.f;
        #pragma unroll 8
        for (int kq = w * 16; kq < w * 16 + 16; kq++) {
          ushort4 wv = wp[(size_t)kq * DD];
          float4 xv = *(const float4*)(y1s + kq * 4);
          acc += xv.x * bf2f(wv.x) + xv.y * bf2f(wv.y) +
                 xv.z * bf2f(wv.z) + xv.w * bf2f(wv.w);
        }
        sPart[tid] = acc;
      }
      __syncthreads();
      float* sQc = sX + 512;
      if (tid < 64) {
        float acc = 0.f;
        #pragma unroll
        for (int i = 0; i < 8; i++) acc += sPart[i * 64 + tid];
        sQc[tid] = acc + P.ca_bq[h * DH + tid];
      }
      __syncthreads();
      // cross-attn scores (d-split)
      {
        int n = tid & 255, dh2 = tid >> 8;
        const ushort_t* kp = P.KcT + ((size_t)b * DD + h * DH) * NN + n;
        float a = 0.f;
        #pragma unroll 8
        for (int i = dh2 * 32; i < dh2 * 32 + 32; i++)
          a += sQc[i] * bf2f(kp[(size_t)i * NN]);
        sPart[tid] = a;
      }
      __syncthreads();
      float* sPr = sX + 1536;
      if (tid < 256) {  // softmax stage 1
        float sc = (sPart[tid] + sPart[256 + tid]) * 0.125f;
        sPr[tid] = sc;
        int w = tid >> 6, lane = tid & 63;
        float mx = sc;
        #pragma unroll
        for (int s = 32; s >= 1; s >>= 1) mx = fmaxf(mx, __shfl_xor(mx, s));
        if (lane == 0) sAux[w] = mx;
      }
      __syncthreads();
      if (tid < 256) {  // softmax stage 2
        int w = tid >> 6, lane = tid & 63;
        float mx = fmaxf(fmaxf(sAux[0], sAux[1]), fmaxf(sAux[2], sAux[3]));
        float e = __expf(sPr[tid] - mx);
        sPr[tid] = e;
        float s2 = e;
        #pragma unroll
        for (int s = 32; s >= 1; s >>= 1) s2 += __shfl_xor(s2, s);
        if (lane == 0) sAux[4 + w] = s2;
      }
      __syncthreads();
      float* sB = sX + 1024;
      {
        int g = tid >> 6, d = tid & 63;
        float inv = 1.f / (sAux[4] + sAux[5] + sAux[6] + sAux[7]);
        const ushort_t* vp = P.VcH + ((size_t)idx8 * NN + g * 32) * DH + d;
        float acc = 0.f;
        #pragma unroll 4
        for (int n = 0; n < 32; n++) acc += sPr[g * 32 + n] * bf2f(vp[(size_t)n * DH]);
        sB[tid] = acc * inv;
      }
      __syncthreads();
      if (tid < 64) {   // aCA head-slice -> sX[0..64)
        float o = 0.f;
        #pragma unroll
        for (int i = 0; i < 8; i++) o += sB[i * 64 + tid];
        sX[tid] = o;
      }
      __syncthreads();
      {  // u2 k-chunk-h partial + atomicAdd (h0 adds bias + y1 residual)
        const ushort4* wp = (const ushort4*)(P.w8 + 7ull * DD * DD) + tid;
        float acc = (h == 0) ? P.ca_bo[tid] + y1s[tid] : 0.f;
        #pragma unroll 8
        for (int j = 0; j < 16; j++) {
          int k4 = h * 16 + j;
          ushort4 wv = wp[(size_t)k4 * DD];
          float4 xv = *(const float4*)(sX + j * 4);
          acc += xv.x * bf2f(wv.x) + xv.y * bf2f(wv.y) +
                 xv.z * bf2f(wv.z) + xv.w * bf2f(wv.w);
        }
        atomicAdd(&P.u2[(size_t)b * DD + tid], acc);
      }
    }
    gbar(cnt, tid, grnd);

    // ==== Phase C: LN2(u2) -> zs ; FFN1 slice ; zero u1 & ctx[(t+1)&1] ======
    {
      float v = ldg_a(P.u2 + (size_t)b * DD + tid);
      {
        int w = tid >> 6, lane = tid & 63;
        float s = v, q2 = v * v;
        #pragma unroll
        for (int m = 32; m >= 1; m >>= 1) { s += __shfl_xor(s, m); q2 += __shfl_xor(q2, m); }
        if (lane == 0) { sAux[w] = s; sAux[8 + w] = q2; }
      }
      __syncthreads();
      {
        float ss = 0.f, qq = 0.f;
        #pragma unroll
        for (int i = 0; i < 8; i++) { ss += sAux[i]; qq += sAux[8 + i]; }
        float mean = ss * (1.f / 512.f);
        float inv = rsqrtf(qq * (1.f / 512.f) - mean * mean + 1e-5f);
        zs[tid] = (v - mean) * inv * P.ln2w[tid] + P.ln2b[tid];
      }
      if (h == 0) {   // re-zero u1 (read in B this step; next add in A(t+1))
        stg_a(&P.u1[(size_t)b * DD + tid], 0.f);
        float* cz = ((t + 1) & 1) ? P.ctx1 : P.ctx0;  // read at E(t-1); add at A(t+1)
        stg_a(&cz[(size_t)b * DD + tid], 0.f);
      }
      __syncthreads();
      {  // FFN1: cols h*256..h*256+255, k split in 2 halves
        int c = tid & 255, half = tid >> 8, col = h * 256 + c;
        const ushort4* wp = (const ushort4*)P.w1b + col;
        float acc = 0.f;
        #pragma unroll 8
        for (int kq = half * 64; kq < half * 64 + 64; kq++) {
          ushort4 wv = wp[(size_t)kq * DF];
          float4 xv = *(const float4*)(zs + kq * 4);
          acc += xv.x * bf2f(wv.x) + xv.y * bf2f(wv.y) +
                 xv.z * bf2f(wv.z) + xv.w * bf2f(wv.w);
        }
        sPart[tid] = acc;
      }
      __syncthreads();
      if (tid < 256) {
        int col = h * 256 + tid;
        float acc = sPart[tid] + sPart[256 + tid] + P.b1[col];
        stg_a(&P.hbuf[(size_t)b * DF + col], fmaxf(acc, 0.f));
      }
    }
    gbar(cnt, tid, grnd);

    // ==== Phase D: u3 slice = zs + b2 + hbuf@W2 cols h ; zero u2 ============
    {
      #pragma unroll
      for (int i = 0; i < 4; i++)
        sX[i * 512 + tid] = ldg_a(P.hbuf + (size_t)b * DF + i * 512 + tid);
      if (h == 0)   // re-zero u2 (read in C this step; next add in B(t+1))
        stg_a(&P.u2[(size_t)b * DD + tid], 0.f);
      __syncthreads();
      {
        int c = tid & 63, kh = tid >> 6, col = h * DH + c;
        const ushort4* wp = (const ushort4*)P.w2b + col;
        float acc = 0.f;
        #pragma unroll 8
        for (int kq = kh * 64; kq < kh * 64 + 64; kq++) {
          ushort4 wv = wp[(size_t)kq * DD];
          float4 xv = *(const float4*)(sX + kq * 4);
          acc += xv.x * bf2f(wv.x) + xv.y * bf2f(wv.y) +
                 xv.z * bf2f(wv.z) + xv.w * bf2f(wv.w);
        }
        sPart[tid] = acc;
      }
      __syncthreads();
      if (tid < 64) {
        int col = h * DH + tid;
        float acc = zs[col] + P.b2[col];
        #pragma unroll
        for (int i = 0; i < 8; i++) acc += sPart[i * 64 + tid];
        stg_a(&P.u3[(size_t)b * DD + col], acc);
      }
    }
    gbar(cnt, tid, grnd);

    // ==== Phase E: nxt = LN3(u3)+ctx ; xrow = nxt+pe[t+1] ; h0: out =========
    {
      float u = ldg_a(P.u3 + (size_t)b * DD + tid);
      {
        int w = tid >> 6, lane = tid & 63;
        float s = u, q2 = u * u;
        #pragma unroll
        for (int m = 32; m >= 1; m >>= 1) { s += __shfl_xor(s, m); q2 += __shfl_xor(q2, m); }
        if (lane == 0) { sAux[w] = s; sAux[8 + w] = q2; }
      }
      __syncthreads();
      float ss = 0.f, qq = 0.f;
      #pragma unroll
      for (int i = 0; i < 8; i++) { ss += sAux[i]; qq += sAux[8 + i]; }
      float mean = ss * (1.f / 512.f);
      float inv = rsqrtf(qq * (1.f / 512.f) - mean * mean + 1e-5f);
      const float* ctxp = (t & 1) ? P.ctx1 : P.ctx0;
      float nxt = (u - mean) * inv * P.ln3w[tid] + P.ln3b[tid] +
                  ldg_a(ctxp + (size_t)b * DD + tid);
      float p = (t < TT - 1) ? P.pe[(size_t)(t + 1) * DD + tid] : 0.f;
      if (h == 0) sX[tid] = nxt;
      __syncthreads();
      xrow[tid] = nxt + p;
      if (h == 0) {   // block-uniform branch: inner barrier legal
        {
          int c = tid >> 8, l = tid & 255;
          float a = sX[l] * P.Wout[(size_t)c * DD + l] +
                    sX[l + 256] * P.Wout[(size_t)c * DD + l + 256];
          #pragma unroll
          for (int m = 32; m >= 1; m >>= 1) a += __shfl_xor(a, m);
          if ((tid & 63) == 0) sAux[16 + (tid >> 6)] = a;
        }
        __syncthreads();
        if (tid == 0)
          P.out[((size_t)b * TT + t) * 2 + 0] =
              sAux[16] + sAux[17] + sAux[18] + sAux[19] + P.bout[0];
        if (tid == 256)
          P.out[((size_t)b * TT + t) * 2 + 1] =
              sAux[20] + sAux[21] + sAux[22] + sAux[23] + P.bout[1];
      }
      __syncthreads();  // xrow/sAux stable before next Phase A
    }
    // no barrier: A(t+1) touches only block-private or opposite-parity state
  }
}

// ---- precompute kernels (unchanged) -----------------------------------------
__global__ __launch_bounds__(256) void gemm_kv(
    const float* __restrict__ A,
    const float* __restrict__ W0, const float* __restrict__ W1_,
    const float* __restrict__ W2_, const float* __restrict__ W3_,
    const float* __restrict__ b0, const float* __restrict__ b1_,
    const float* __restrict__ b2_, const float* __restrict__ b3_,
    float* __restrict__ O0, float* __restrict__ O1,
    float* __restrict__ O2, float* __restrict__ O3) {
  __shared__ __align__(16) float As[8][128];
  __shared__ __align__(16) float Bs[8][128];
  int tid = threadIdx.x;
  int bx = blockIdx.x, by = blockIdx.y;
  int mm = bx >> 2;
  int col0 = (bx & 3) * 128;
  const float* W = mm == 0 ? W0 : mm == 1 ? W1_ : mm == 2 ? W2_ : W3_;
  const float* bias = mm == 0 ? b0 : mm == 1 ? b1_ : mm == 2 ? b2_ : b3_;
  float* O = mm == 0 ? O0 : mm == 1 ? O1 : mm == 2 ? O2 : O3;
  int tx = tid & 15, ty = tid >> 4;
  int m0 = by * 128;
  int lr = tid >> 1, lk = (tid & 1) * 4;
  const float* Ap = A + (size_t)(m0 + lr) * DD + lk;
  const float* Wp = W + (size_t)(col0 + lr) * DD + lk;
  float c[8][8] = {};
  for (int k0 = 0; k0 < DD; k0 += 8) {
    float4 av = *(const float4*)(Ap + k0);
    float4 wv = *(const float4*)(Wp + k0);
    __syncthreads();
    As[lk + 0][lr] = av.x; As[lk + 1][lr] = av.y; As[lk + 2][lr] = av.z; As[lk + 3][lr] = av.w;
    Bs[lk + 0][lr] = wv.x; Bs[lk + 1][lr] = wv.y; Bs[lk + 2][lr] = wv.z; Bs[lk + 3][lr] = wv.w;
    __syncthreads();
    #pragma unroll
    for (int k = 0; k < 8; k++) {
      float a[8], bb[8];
      *(float4*)&a[0] = *(const float4*)&As[k][ty * 8];
      *(float4*)&a[4] = *(const float4*)&As[k][ty * 8 + 4];
      *(float4*)&bb[0] = *(const float4*)&Bs[k][tx * 8];
      *(float4*)&bb[4] = *(const float4*)&Bs[k][tx * 8 + 4];
      #pragma unroll
      for (int i = 0; i < 8; i++)
        #pragma unroll
        for (int j = 0; j < 8; j++) c[i][j] += a[i] * bb[j];
    }
  }
  const float* bp = bias + col0 + tx * 8;
  for (int i = 0; i < 8; i++) {
    int row = m0 + ty * 8 + i;
    float* op = O + (size_t)row * DD + col0 + tx * 8;
    #pragma unroll
    for (int jq = 0; jq < 8; jq += 4) {
      float4 v;
      v.x = c[i][jq + 0] + bp[jq + 0];
      v.y = c[i][jq + 1] + bp[jq + 1];
      v.z = c[i][jq + 2] + bp[jq + 2];
      v.w = c[i][jq + 3] + bp[jq + 3];
      *(float4*)(op + jq) = v;
    }
  }
}

__global__ __launch_bounds__(256) void pack_kT(const float* __restrict__ Ks32,
                                               const float* __restrict__ Kc32,
                                               ushort_t* __restrict__ KsT,
                                               ushort_t* __restrict__ KcT) {
  int z = blockIdx.z;
  int b = z >> 1;
  const float* in = ((z & 1) ? Kc32 : Ks32) + (size_t)b * NN * DD;
  ushort_t* out = ((z & 1) ? KcT : KsT) + (size_t)b * NN * DD;
  int r0 = blockIdx.x * 32, c0 = blockIdx.y * 32;
  __shared__ float tile[32][33];
  int tid = threadIdx.x;
  int i = tid >> 3, j4 = (tid & 7) * 4;
  float4 v = *(const float4*)(in + (size_t)(r0 + i) * DD + c0 + j4);
  tile[i][j4] = v.x; tile[i][j4 + 1] = v.y; tile[i][j4 + 2] = v.z; tile[i][j4 + 3] = v.w;
  __syncthreads();
  ushort_t* op = out + (size_t)(c0 + i) * NN + r0 + j4;
  op[0] = f2bf(tile[j4][i]); op[1] = f2bf(tile[j4 + 1][i]);
  op[2] = f2bf(tile[j4 + 2][i]); op[3] = f2bf(tile[j4 + 3][i]);
}

__global__ __launch_bounds__(256) void pack_vh(const float* __restrict__ Vs32,
                                               const float* __restrict__ Vc32,
                                               ushort_t* __restrict__ VsH,
                                               ushort_t* __restrict__ VcH) {
  const float* src = blockIdx.y ? Vc32 : Vs32;
  ushort_t* dst = blockIdx.y ? VcH : VsH;
  size_t idx = (size_t)blockIdx.x * 1024 + threadIdx.x * 4;
  float4 v = *(const float4*)(src + idx);
  int d512 = (int)(idx & 511);
  int n = (int)((idx >> 9) & 255);
  int b = (int)(idx >> 17);
  int h = d512 >> 6, d = d512 & 63;
  ushort_t* op = dst + (((size_t)(b * 8 + h) * NN + n) * DH + d);
  op[0] = f2bf(v.x); op[1] = f2bf(v.y); op[2] = f2bf(v.z); op[3] = f2bf(v.w);
}

struct PWItem { const float* in; ushort_t* out; int C; int K; };
struct PWArgs { PWItem m[10]; };
__global__ __launch_bounds__(256) void pack_w(PWArgs a) {
  PWItem it = a.m[blockIdx.y];
  int total = it.C * (it.K >> 2);
  int e = blockIdx.x * 256 + threadIdx.x;
  if (e >= total) return;
  int kd = it.K >> 2;
  int k4 = e % kd, col = e / kd;
  float4 v = *(const float4*)(it.in + (size_t)col * it.K + k4 * 4);
  ushort4 o;
  o.x = f2bf(v.x); o.y = f2bf(v.y); o.z = f2bf(v.z); o.w = f2bf(v.w);
  *((ushort4*)it.out + (size_t)k4 * it.C + col) = o;
}

__global__ __launch_bounds__(256) void init_x(const float* __restrict__ hv0,
                                              const float* __restrict__ pe,
                                              float* __restrict__ ws,
                                              unsigned* __restrict__ flags) {
  int i = blockIdx.x * 256 + threadIdx.x;
  ws[OFF_X + i] = hv0[i] + pe[i & (DD - 1)];
  ws[OFF_U1 + i] = 0.f;
  ws[OFF_U2 + i] = 0.f;
  ws[OFF_CT0 + i] = 0.f;
  ws[OFF_CT1 + i] = 0.f;
  if (i < 1024) flags[i] = 0u;
}

// ---------------------------------------------------------------------------
extern "C" void kernel_launch(void* const* d_in, const int* in_sizes, int n_in,
                              void* d_out, int out_size, void* d_ws, size_t ws_size,
                              hipStream_t stream) {
  const float* H_v_all = (const float*)d_in[0];
  const float* H_v0    = (const float*)d_in[1];
  const float* pe      = (const float*)d_in[2];
  const float* s_Wq = (const float*)d_in[3];
  const float* s_Wk = (const float*)d_in[4];
  const float* s_Wv = (const float*)d_in[5];
  const float* s_Wo = (const float*)d_in[6];
  const float* s_bq = (const float*)d_in[7];
  const float* s_bk = (const float*)d_in[8];
  const float* s_bv = (const float*)d_in[9];
  const float* s_bo = (const float*)d_in[10];
  const float* sa_Wq = (const float*)d_in[11];
  const float* sa_Wk = (const float*)d_in[12];
  const float* sa_Wv = (const float*)d_in[13];
  const float* sa_Wo = (const float*)d_in[14];
  const float* sa_bq = (const float*)d_in[15];
  const float* sa_bk = (const float*)d_in[16];
  const float* sa_bv = (const float*)d_in[17];
  const float* sa_bo = (const float*)d_in[18];
  const float* ca_Wq = (const float*)d_in[19];
  const float* ca_Wk = (const float*)d_in[20];
  const float* ca_Wv = (const float*)d_in[21];
  const float* ca_Wo = (const float*)d_in[22];
  const float* ca_bq = (const float*)d_in[23];
  const float* ca_bk = (const float*)d_in[24];
  const float* ca_bv = (const float*)d_in[25];
  const float* ca_bo = (const float*)d_in[26];
  const float* ln1w = (const float*)d_in[27];
  const float* ln1b = (const float*)d_in[28];
  const float* ln2w = (const float*)d_in[29];
  const float* ln2b = (const float*)d_in[30];
  const float* ln3w = (const float*)d_in[31];
  const float* ln3b = (const float*)d_in[32];
  const float* W1   = (const float*)d_in[33];
  const float* b1   = (const float*)d_in[34];
  const float* W2   = (const float*)d_in[35];
  const float* b2   = (const float*)d_in[36];
  const float* Wout = (const float*)d_in[37];
  const float* bout = (const float*)d_in[38];

  float* ws = (float*)d_ws;
  float* Ks32 = ws + OFF_KS32;
  float* Vs32 = ws + OFF_VS32;
  float* Kc32 = ws + OFF_KC32;
  float* Vc32 = ws + OFF_VC32;
  ushort_t* ub = (ushort_t*)(ws + OFF_BF);
  unsigned* flags = (unsigned*)(ws + OFF_FLG);

  hipLaunchKernelGGL(gemm_kv, dim3(16, 64), dim3(256), 0, stream,
                     H_v_all, s_Wk, s_Wv, ca_Wk, ca_Wv,
                     s_bk, s_bv, ca_bk, ca_bv, Ks32, Vs32, Kc32, Vc32);

  hipLaunchKernelGGL(pack_kT, dim3(8, 16, 64), dim3(256), 0, stream,
                     Ks32, Kc32, ub + UOFF_KST, ub + UOFF_KCT);
  hipLaunchKernelGGL(pack_vh, dim3((unsigned)(SZ_KV / 1024), 2), dim3(256), 0,
                     stream, Vs32, Vc32, ub + UOFF_VSH, ub + UOFF_VCH);

  PWArgs pw;
  pw.m[0] = {sa_Wq, ub + UOFF_W8 + 0ull * DD * DD, DD, DD};
  pw.m[1] = {sa_Wk, ub + UOFF_W8 + 1ull * DD * DD, DD, DD};
  pw.m[2] = {sa_Wv, ub + UOFF_W8 + 2ull * DD * DD, DD, DD};
  pw.m[3] = {s_Wq,  ub + UOFF_W8 + 3ull * DD * DD, DD, DD};
  pw.m[4] = {sa_Wo, ub + UOFF_W8 + 4ull * DD * DD, DD, DD};
  pw.m[5] = {s_Wo,  ub + UOFF_W8 + 5ull * DD * DD, DD, DD};
  pw.m[6] = {ca_Wq, ub + UOFF_W8 + 6ull * DD * DD, DD, DD};
  pw.m[7] = {ca_Wo, ub + UOFF_W8 + 7ull * DD * DD, DD, DD};
  pw.m[8] = {W1, ub + UOFF_W1, DF, DD};
  pw.m[9] = {W2, ub + UOFF_W2, DD, DF};
  hipLaunchKernelGGL(pack_w, dim3(1024, 10), dim3(256), 0, stream, pw);

  hipLaunchKernelGGL(init_x, dim3(64), dim3(256), 0, stream,
                     H_v0, pe, ws, flags);

  Params P;
  P.pe = pe;
  P.sa_bq = sa_bq; P.sa_bk = sa_bk; P.sa_bv = sa_bv; P.s_bq = s_bq;
  P.sa_bo = sa_bo; P.s_bo = s_bo; P.ca_bq = ca_bq; P.ca_bo = ca_bo;
  P.ln1w = ln1w; P.ln1b = ln1b; P.ln2w = ln2w; P.ln2b = ln2b;
  P.ln3w = ln3w; P.ln3b = ln3b;
  P.b1 = b1; P.b2 = b2; P.Wout = Wout; P.bout = bout;
  P.w8 = ub + UOFF_W8; P.w1b = ub + UOFF_W1; P.w2b = ub + UOFF_W2;
  P.KsT = ub + UOFF_KST; P.KcT = ub + UOFF_KCT;
  P.VsH = ub + UOFF_VSH; P.VcH = ub + UOFF_VCH;
  P.KsaB = ub + UOFF_KSA; P.VsaB = ub + UOFF_VSA;
  P.xcur = ws + OFF_X;
  P.u1 = ws + OFF_U1; P.u2 = ws + OFF_U2; P.u3 = ws + OFF_U3;
  P.hbuf = ws + OFF_H; P.ctx0 = ws + OFF_CT0; P.ctx1 = ws + OFF_CT1;
  P.out = (float*)d_out;
  P.flags = flags;

  void* kargs[] = { (void*)&P };
  hipLaunchCooperativeKernel((void*)decode_persistent, dim3(NBLK), dim3(NTHR),
                             kargs, 0, stream);
}

// Round 2
// 5358.765 us; speedup vs baseline: 1.0424x; 1.0424x over previous
//
#include <hip/hip_runtime.h>

// ---------------------------------------------------------------------------
// VehicleTrajectoryDecoder: B=32, N=256, D=512, H=8 (dh=64), T=60, DFF=2048.
// R11: R10 regressed 3269->5232us because the b=bid&31 mapping destroyed the
// implicit XCD weight partitioning (XCD = bid mod 8 = h in R9): FETCH_SIZE
// doubled, VALUBusy fell to 13.7%. R11 restores b=bid>>3, h=bid&7 (head ==
// XCD; all weight slices are functions of h only -> each XCD L2 holds 1/8 of
// weights) while KEEPING the R10 fusion: per-batch 8-block barriers, Wo
// partials folded into attention phases, x_next in LDS. NEW: FFN2 fused into
// phase C (block (b,h) computes its 256 hidden values, then the k-chunk-h
// partial of u3 via W2 row-slice + atomicAdd) -> phase D, its barrier, and
// the hbuf round trip are gone. 3 barriers/step (R9: 7). Zeroing schedule:
// u1 in C, u2 in E, u3 & ctx[(t+1)&1] in B - each >=1 barrier away from
// both reader and next writer. All barriers full-block (R8/R9 lesson).
// ---------------------------------------------------------------------------

#define NB 32
#define NN 256
#define DD 512
#define NH 8
#define DH 64
#define TT 60
#define DF 2048
#define NBLK 256
#define NTHR 512

typedef unsigned short ushort_t;

// ---- workspace layout ------------------------------------------------------
constexpr size_t SZ_KV  = (size_t)NB * NN * DD;   // 4194304
constexpr size_t SZ_ROW = (size_t)NB * DD;
constexpr size_t SZ_SAB = (size_t)NB * NH * TT * DH;
constexpr size_t OFF_KS32 = 0;
constexpr size_t OFF_VS32 = SZ_KV;
constexpr size_t OFF_KC32 = 2 * SZ_KV;
constexpr size_t OFF_VC32 = 3 * SZ_KV;
constexpr size_t OFF_X   = 0;
constexpr size_t OFF_CT1 = OFF_X   + SZ_ROW;
constexpr size_t OFF_U1  = OFF_CT1 + SZ_ROW;
constexpr size_t OFF_U2  = OFF_U1  + SZ_ROW;
constexpr size_t OFF_CT0 = OFF_U2  + SZ_ROW;
constexpr size_t OFF_U3  = OFF_CT0 + SZ_ROW;
constexpr size_t OFF_BF   = 4 * SZ_KV;
constexpr size_t UOFF_KST = 0;
constexpr size_t UOFF_KCT = SZ_KV;
constexpr size_t UOFF_VSH = 2 * SZ_KV;
constexpr size_t UOFF_VCH = 3 * SZ_KV;
constexpr size_t UOFF_KSA = 4 * SZ_KV;
constexpr size_t UOFF_VSA = UOFF_KSA + SZ_SAB;
constexpr size_t UOFF_W8  = UOFF_VSA + SZ_SAB;
constexpr size_t UOFF_W1  = UOFF_W8 + 8ull * DD * DD;
constexpr size_t UOFF_W2  = UOFF_W1 + (size_t)DD * DF;
constexpr size_t UEND     = UOFF_W2 + (size_t)DF * DD;
constexpr size_t OFF_FLG  = OFF_BF + (UEND + 1) / 2;

// ---- helpers ----------------------------------------------------------------
__device__ __forceinline__ float ldg_a(const float* p) {
  return __hip_atomic_load(p, __ATOMIC_RELAXED, __HIP_MEMORY_SCOPE_AGENT);
}
__device__ __forceinline__ void stg_a(float* p, float v) {
  __hip_atomic_store(p, v, __ATOMIC_RELAXED, __HIP_MEMORY_SCOPE_AGENT);
}
__device__ __forceinline__ float bf2f(ushort_t u) {
  return __uint_as_float(((unsigned)u) << 16);
}
__device__ __forceinline__ ushort_t f2bf(float f) {
  unsigned u = __float_as_uint(f);
  return (ushort_t)((u + 0x7FFFu + ((u >> 16) & 1u)) >> 16);
}

// ---- params ----------------------------------------------------------------
struct Params {
  const float *pe;
  const float *sa_bq, *sa_bk, *sa_bv, *s_bq, *sa_bo, *s_bo, *ca_bq, *ca_bo;
  const float *ln1w, *ln1b, *ln2w, *ln2b, *ln3w, *ln3b;
  const float *b1, *b2, *Wout, *bout;
  const ushort_t *w8, *w1b, *w2b;
  const ushort_t *KsT, *KcT, *VsH, *VcH;
  ushort_t *KsaB, *VsaB;
  float *xcur, *u1, *u2, *u3, *ctx0, *ctx1;
  float *out;
  unsigned *flags;
};

// ---- per-batch 8-block barrier (monotonic counter, 128B-spaced lines) ------
__device__ __forceinline__ void gbar(unsigned* cnt, int tid, unsigned& grnd) {
  __builtin_amdgcn_s_waitcnt(0);
  __syncthreads();
  grnd += NH;
  if (tid == 0) {
    __hip_atomic_fetch_add(cnt, 1u, __ATOMIC_RELAXED, __HIP_MEMORY_SCOPE_AGENT);
    while (__hip_atomic_load(cnt, __ATOMIC_RELAXED,
                             __HIP_MEMORY_SCOPE_AGENT) < grnd)
      __builtin_amdgcn_s_sleep(1);
  }
  __syncthreads();
}

// ---- persistent decode (256 blocks x 512 threads; 32 batches x 8 heads) ----
__global__ __launch_bounds__(512) void decode_persistent(Params P) {
  __shared__ __align__(16) float sX[2048];    // scratch
  __shared__ __align__(16) float sPart[512];
  __shared__ float sAux[64];
  __shared__ __align__(16) float xrow[512];   // persistent x (incl. pe)
  __shared__ __align__(16) float y1s[512];    // LN1 output row
  __shared__ __align__(16) float zs[512];     // LN2 output row
  int tid = threadIdx.x;
  int bid = blockIdx.x;
  int b = bid >> 3, h = bid & 7;              // XCD = bid mod 8 = h  (key!)
  int idx8 = bid;                             // (b,h) linear index
  unsigned* cnt = P.flags + b * 32;           // 128B apart
  unsigned grnd = 0;

  xrow[tid] = ldg_a(P.xcur + (size_t)b * DD + tid);
  __syncthreads();

  for (int t = 0; t < TT; t++) {
    // ==== Phase A: proj q/k/v/qs + self-attn + spatial + u1/ctx partials ====
    {
      // proj: wave w: matrix m=w>>1, k-half=w&1; lane c -> col h*64+c
      {
        int w = tid >> 6, c = tid & 63, m = w >> 1, half = w & 1;
        int col = h * DH + c;
        const ushort4* wp = (const ushort4*)(P.w8 + (size_t)m * DD * DD) + col;
        float acc = 0.f;
        #pragma unroll 8
        for (int kq = half * 64; kq < half * 64 + 64; kq++) {
          ushort4 wv = wp[(size_t)kq * DD];
          float4 xv = *(const float4*)(xrow + kq * 4);
          acc += xv.x * bf2f(wv.x) + xv.y * bf2f(wv.y) +
                 xv.z * bf2f(wv.z) + xv.w * bf2f(wv.w);
        }
        sPart[tid] = acc;
      }
      __syncthreads();
      if (tid < 256) {  // combine halves + bias; stash in sX[512..768)
        int m = tid >> 6, c = tid & 63, col = h * DH + c;
        const float* bias = (m == 0) ? P.sa_bq : (m == 1) ? P.sa_bk
                          : (m == 2) ? P.sa_bv : P.s_bq;
        float val = sPart[(2 * m) * 64 + c] + sPart[(2 * m + 1) * 64 + c]
                    + bias[col];
        sX[512 + tid] = val;
        if (m == 1) P.KsaB[((size_t)idx8 * TT + t) * DH + c] = f2bf(val);
        if (m == 2) P.VsaB[((size_t)idx8 * TT + t) * DH + c] = f2bf(val);
      }
      __syncthreads();

      // ---- self-attn over L keys (head-private bf16 cache) ----
      int L = t + 1;
      float* sQ  = sX + 512;        // q_self [64]
      float* sQs = sX + 704;        // q_spatial [64]
      float* sPb = sX + 768;        // self probs [64]
      float* sB  = sX + 1024;       // partials [512]
      if (tid < 64) {
        float sc = -1e30f;
        if (tid < L) {
          const ushort_t* kp = P.KsaB + ((size_t)idx8 * TT + tid) * DH;
          float a = 0.f;
          #pragma unroll
          for (int i = 0; i < DH; i += 4) {
            ushort4 kv = *(const ushort4*)(kp + i);
            a += sQ[i] * bf2f(kv.x) + sQ[i + 1] * bf2f(kv.y) +
                 sQ[i + 2] * bf2f(kv.z) + sQ[i + 3] * bf2f(kv.w);
          }
          sc = a * 0.125f;
        }
        float mx = sc;
        #pragma unroll
        for (int s = 32; s >= 1; s >>= 1) mx = fmaxf(mx, __shfl_xor(mx, s));
        float e = (tid < L) ? __expf(sc - mx) : 0.f;
        float s2 = e;
        #pragma unroll
        for (int s = 32; s >= 1; s >>= 1) s2 += __shfl_xor(s2, s);
        sPb[tid] = e;
        if (tid == 0) sAux[12] = 1.f / s2;
      }
      __syncthreads();
      {  // PV: 8 key-groups x 64 d
        int g = tid >> 6, d = tid & 63;
        float a2 = 0.f;
        for (int j = g; j < L; j += 8)
          a2 += sPb[j] * bf2f(P.VsaB[((size_t)idx8 * TT + j) * DH + d]);
        sB[tid] = a2;
      }
      __syncthreads();
      if (tid < 64) {   // aSA head-slice -> sX[0..64)
        float o = 0.f;
        #pragma unroll
        for (int i = 0; i < 8; i++) o += sB[i * 64 + tid];
        sX[tid] = o * sAux[12];
      }
      __syncthreads();

      // ---- spatial attn over 256 keys (d-split scores, 8-way PV) ----
      {
        int n = tid & 255, dh2 = tid >> 8;
        const ushort_t* kp = P.KsT + ((size_t)b * DD + h * DH) * NN + n;
        float a = 0.f;
        #pragma unroll 8
        for (int i = dh2 * 32; i < dh2 * 32 + 32; i++)
          a += sQs[i] * bf2f(kp[(size_t)i * NN]);
        sPart[tid] = a;
      }
      __syncthreads();
      float* sPr = sX + 1536;  // spatial probs [256]
      if (tid < 256) {  // softmax stage 1 (full-block sync'd)
        float sc = (sPart[tid] + sPart[256 + tid]) * 0.125f;
        sPr[tid] = sc;
        int w = tid >> 6, lane = tid & 63;
        float mx = sc;
        #pragma unroll
        for (int s = 32; s >= 1; s >>= 1) mx = fmaxf(mx, __shfl_xor(mx, s));
        if (lane == 0) sAux[w] = mx;
      }
      __syncthreads();
      if (tid < 256) {  // softmax stage 2
        int w = tid >> 6, lane = tid & 63;
        float mx = fmaxf(fmaxf(sAux[0], sAux[1]), fmaxf(sAux[2], sAux[3]));
        float e = __expf(sPr[tid] - mx);
        sPr[tid] = e;
        float s2 = e;
        #pragma unroll
        for (int s = 32; s >= 1; s >>= 1) s2 += __shfl_xor(s2, s);
        if (lane == 0) sAux[4 + w] = s2;
      }
      __syncthreads();
      {
        int g = tid >> 6, d = tid & 63;
        float inv = 1.f / (sAux[4] + sAux[5] + sAux[6] + sAux[7]);
        const ushort_t* vp = P.VsH + ((size_t)idx8 * NN + g * 32) * DH + d;
        float acc = 0.f;
        #pragma unroll 4
        for (int n = 0; n < 32; n++) acc += sPr[g * 32 + n] * bf2f(vp[(size_t)n * DH]);
        sB[tid] = acc * inv;
      }
      __syncthreads();
      if (tid < 64) {   // aSP head-slice -> sX[64..128)
        float o = 0.f;
        #pragma unroll
        for (int i = 0; i < 8; i++) o += sB[i * 64 + tid];
        sX[64 + tid] = o;
      }
      __syncthreads();

      // ---- u1/ctx k-chunk-h partials: row-slice gemv + atomicAdd ----
      {
        float* ctxp = (t & 1) ? P.ctx1 : P.ctx0;
        const ushort4* wpa = (const ushort4*)(P.w8 + 4ull * DD * DD) + tid;
        const ushort4* wpb = (const ushort4*)(P.w8 + 5ull * DD * DD) + tid;
        float acc1 = (h == 0) ? P.sa_bo[tid] + xrow[tid] : 0.f;
        float acc2 = (h == 0) ? P.s_bo[tid] : 0.f;
        #pragma unroll 8
        for (int j = 0; j < 16; j++) {
          int k4 = h * 16 + j;
          ushort4 wv = wpa[(size_t)k4 * DD];
          float4 xv = *(const float4*)(sX + j * 4);
          acc1 += xv.x * bf2f(wv.x) + xv.y * bf2f(wv.y) +
                  xv.z * bf2f(wv.z) + xv.w * bf2f(wv.w);
          ushort4 wv2 = wpb[(size_t)k4 * DD];
          float4 xv2 = *(const float4*)(sX + 64 + j * 4);
          acc2 += xv2.x * bf2f(wv2.x) + xv2.y * bf2f(wv2.y) +
                  xv2.z * bf2f(wv2.z) + xv2.w * bf2f(wv2.w);
        }
        atomicAdd(&P.u1[(size_t)b * DD + tid], acc1);
        atomicAdd(&ctxp[(size_t)b * DD + tid], acc2);
      }
    }
    gbar(cnt, tid, grnd);

    // ==== Phase B: LN1(u1)->y1s ; zero u3,ctx[(t+1)&1] ; qc ; cross ; u2 ===
    {
      float u = ldg_a(P.u1 + (size_t)b * DD + tid);
      if (h == 0) {  // u3: E(t-1) readers done (A-bar); C(t) adds after B-bar
        stg_a(&P.u3[(size_t)b * DD + tid], 0.f);
        // ctx[(t+1)&1]: read at E(t-1) (done via A-bar); added at A(t+1)
        float* cz = ((t + 1) & 1) ? P.ctx1 : P.ctx0;
        stg_a(&cz[(size_t)b * DD + tid], 0.f);
      }
      {
        int w = tid >> 6, lane = tid & 63;
        float s = u, q2 = u * u;
        #pragma unroll
        for (int m = 32; m >= 1; m >>= 1) { s += __shfl_xor(s, m); q2 += __shfl_xor(q2, m); }
        if (lane == 0) { sAux[w] = s; sAux[8 + w] = q2; }
      }
      __syncthreads();
      {
        float ss = 0.f, qq = 0.f;
        #pragma unroll
        for (int i = 0; i < 8; i++) { ss += sAux[i]; qq += sAux[8 + i]; }
        float mean = ss * (1.f / 512.f);
        float inv = rsqrtf(qq * (1.f / 512.f) - mean * mean + 1e-5f);
        y1s[tid] = (u - mean) * inv * P.ln1w[tid] + P.ln1b[tid];
      }
      __syncthreads();
      {  // qc: 8 k-chunks of 64
        int c = tid & 63, w = tid >> 6, col = h * DH + c;
        const ushort4* wp = (const ushort4*)(P.w8 + 6ull * DD * DD) + col;
        float acc = 0.f;
        #pragma unroll 8
        for (int kq = w * 16; kq < w * 16 + 16; kq++) {
          ushort4 wv = wp[(size_t)kq * DD];
          float4 xv = *(const float4*)(y1s + kq * 4);
          acc += xv.x * bf2f(wv.x) + xv.y * bf2f(wv.y) +
                 xv.z * bf2f(wv.z) + xv.w * bf2f(wv.w);
        }
        sPart[tid] = acc;
      }
      __syncthreads();
      float* sQc = sX + 512;
      if (tid < 64) {
        float acc = 0.f;
        #pragma unroll
        for (int i = 0; i < 8; i++) acc += sPart[i * 64 + tid];
        sQc[tid] = acc + P.ca_bq[h * DH + tid];
      }
      __syncthreads();
      // cross-attn scores (d-split)
      {
        int n = tid & 255, dh2 = tid >> 8;
        const ushort_t* kp = P.KcT + ((size_t)b * DD + h * DH) * NN + n;
        float a = 0.f;
        #pragma unroll 8
        for (int i = dh2 * 32; i < dh2 * 32 + 32; i++)
          a += sQc[i] * bf2f(kp[(size_t)i * NN]);
        sPart[tid] = a;
      }
      __syncthreads();
      float* sPr = sX + 1536;
      if (tid < 256) {  // softmax stage 1
        float sc = (sPart[tid] + sPart[256 + tid]) * 0.125f;
        sPr[tid] = sc;
        int w = tid >> 6, lane = tid & 63;
        float mx = sc;
        #pragma unroll
        for (int s = 32; s >= 1; s >>= 1) mx = fmaxf(mx, __shfl_xor(mx, s));
        if (lane == 0) sAux[w] = mx;
      }
      __syncthreads();
      if (tid < 256) {  // softmax stage 2
        int w = tid >> 6, lane = tid & 63;
        float mx = fmaxf(fmaxf(sAux[0], sAux[1]), fmaxf(sAux[2], sAux[3]));
        float e = __expf(sPr[tid] - mx);
        sPr[tid] = e;
        float s2 = e;
        #pragma unroll
        for (int s = 32; s >= 1; s >>= 1) s2 += __shfl_xor(s2, s);
        if (lane == 0) sAux[4 + w] = s2;
      }
      __syncthreads();
      float* sB = sX + 1024;
      {
        int g = tid >> 6, d = tid & 63;
        float inv = 1.f / (sAux[4] + sAux[5] + sAux[6] + sAux[7]);
        const ushort_t* vp = P.VcH + ((size_t)idx8 * NN + g * 32) * DH + d;
        float acc = 0.f;
        #pragma unroll 4
        for (int n = 0; n < 32; n++) acc += sPr[g * 32 + n] * bf2f(vp[(size_t)n * DH]);
        sB[tid] = acc * inv;
      }
      __syncthreads();
      if (tid < 64) {   // aCA head-slice -> sX[0..64)
        float o = 0.f;
        #pragma unroll
        for (int i = 0; i < 8; i++) o += sB[i * 64 + tid];
        sX[tid] = o;
      }
      __syncthreads();
      {  // u2 k-chunk-h partial + atomicAdd (h0 adds bias + y1 residual)
        const ushort4* wp = (const ushort4*)(P.w8 + 7ull * DD * DD) + tid;
        float acc = (h == 0) ? P.ca_bo[tid] + y1s[tid] : 0.f;
        #pragma unroll 8
        for (int j = 0; j < 16; j++) {
          int k4 = h * 16 + j;
          ushort4 wv = wp[(size_t)k4 * DD];
          float4 xv = *(const float4*)(sX + j * 4);
          acc += xv.x * bf2f(wv.x) + xv.y * bf2f(wv.y) +
                 xv.z * bf2f(wv.z) + xv.w * bf2f(wv.w);
        }
        atomicAdd(&P.u2[(size_t)b * DD + tid], acc);
      }
    }
    gbar(cnt, tid, grnd);

    // ==== Phase C: LN2(u2)->zs ; zero u1 ; FFN1 slice ; fused FFN2 partial ==
    {
      float v = ldg_a(P.u2 + (size_t)b * DD + tid);
      if (h == 0)   // u1: read in B(t); next adds A(t+1) (after C-bar + E)
        stg_a(&P.u1[(size_t)b * DD + tid], 0.f);
      {
        int w = tid >> 6, lane = tid & 63;
        float s = v, q2 = v * v;
        #pragma unroll
        for (int m = 32; m >= 1; m >>= 1) { s += __shfl_xor(s, m); q2 += __shfl_xor(q2, m); }
        if (lane == 0) { sAux[w] = s; sAux[8 + w] = q2; }
      }
      __syncthreads();
      {
        float ss = 0.f, qq = 0.f;
        #pragma unroll
        for (int i = 0; i < 8; i++) { ss += sAux[i]; qq += sAux[8 + i]; }
        float mean = ss * (1.f / 512.f);
        float inv = rsqrtf(qq * (1.f / 512.f) - mean * mean + 1e-5f);
        zs[tid] = (v - mean) * inv * P.ln2w[tid] + P.ln2b[tid];
      }
      __syncthreads();
      {  // FFN1: cols h*256..h*256+255, k split in 2 halves
        int c = tid & 255, half = tid >> 8, col = h * 256 + c;
        const ushort4* wp = (const ushort4*)P.w1b + col;
        float acc = 0.f;
        #pragma unroll 8
        for (int kq = half * 64; kq < half * 64 + 64; kq++) {
          ushort4 wv = wp[(size_t)kq * DF];
          float4 xv = *(const float4*)(zs + kq * 4);
          acc += xv.x * bf2f(wv.x) + xv.y * bf2f(wv.y) +
                 xv.z * bf2f(wv.z) + xv.w * bf2f(wv.w);
        }
        sPart[tid] = acc;
      }
      __syncthreads();
      float* hh = sX;  // relu hidden slice [256]
      if (tid < 256)
        hh[tid] = fmaxf(sPart[tid] + sPart[256 + tid] + P.b1[h * 256 + tid], 0.f);
      __syncthreads();
      {  // fused FFN2: u3 partial over k-chunk h (W2 rows h*256..h*256+255)
        const ushort4* wp = (const ushort4*)P.w2b + tid;
        float acc = (h == 0) ? zs[tid] + P.b2[tid] : 0.f;
        #pragma unroll 8
        for (int j = 0; j < 64; j++) {
          int k4 = h * 64 + j;
          ushort4 wv = wp[(size_t)k4 * DD];
          float4 xv = *(const float4*)(hh + j * 4);
          acc += xv.x * bf2f(wv.x) + xv.y * bf2f(wv.y) +
                 xv.z * bf2f(wv.z) + xv.w * bf2f(wv.w);
        }
        atomicAdd(&P.u3[(size_t)b * DD + tid], acc);
      }
    }
    gbar(cnt, tid, grnd);

    // ==== Phase E: nxt = LN3(u3)+ctx ; zero u2 ; xrow=nxt+pe ; h0: out ======
    {
      float u = ldg_a(P.u3 + (size_t)b * DD + tid);
      if (h == 0)   // u2: read in C(t); next adds B(t+1) (after E + A-bar)
        stg_a(&P.u2[(size_t)b * DD + tid], 0.f);
      {
        int w = tid >> 6, lane = tid & 63;
        float s = u, q2 = u * u;
        #pragma unroll
        for (int m = 32; m >= 1; m >>= 1) { s += __shfl_xor(s, m); q2 += __shfl_xor(q2, m); }
        if (lane == 0) { sAux[w] = s; sAux[8 + w] = q2; }
      }
      __syncthreads();
      float ss = 0.f, qq = 0.f;
      #pragma unroll
      for (int i = 0; i < 8; i++) { ss += sAux[i]; qq += sAux[8 + i]; }
      float mean = ss * (1.f / 512.f);
      float inv = rsqrtf(qq * (1.f / 512.f) - mean * mean + 1e-5f);
      const float* ctxp = (t & 1) ? P.ctx1 : P.ctx0;
      float nxt = (u - mean) * inv * P.ln3w[tid] + P.ln3b[tid] +
                  ldg_a(ctxp + (size_t)b * DD + tid);
      float p = (t < TT - 1) ? P.pe[(size_t)(t + 1) * DD + tid] : 0.f;
      if (h == 0) sX[tid] = nxt;
      __syncthreads();
      xrow[tid] = nxt + p;
      if (h == 0) {   // block-uniform branch: inner barrier legal
        {
          int c = tid >> 8, l = tid & 255;
          float a = sX[l] * P.Wout[(size_t)c * DD + l] +
                    sX[l + 256] * P.Wout[(size_t)c * DD + l + 256];
          #pragma unroll
          for (int m = 32; m >= 1; m >>= 1) a += __shfl_xor(a, m);
          if ((tid & 63) == 0) sAux[16 + (tid >> 6)] = a;
        }
        __syncthreads();
        if (tid == 0)
          P.out[((size_t)b * TT + t) * 2 + 0] =
              sAux[16] + sAux[17] + sAux[18] + sAux[19] + P.bout[0];
        if (tid == 256)
          P.out[((size_t)b * TT + t) * 2 + 1] =
              sAux[20] + sAux[21] + sAux[22] + sAux[23] + P.bout[1];
      }
      __syncthreads();  // xrow/sAux stable before next Phase A
    }
    // no barrier: A(t+1) touches only block-private or re-zeroed state
  }
}

// ---- precompute kernels -----------------------------------------------------
__global__ __launch_bounds__(256) void gemm_kv(
    const float* __restrict__ A,
    const float* __restrict__ W0, const float* __restrict__ W1_,
    const float* __restrict__ W2_, const float* __restrict__ W3_,
    const float* __restrict__ b0, const float* __restrict__ b1_,
    const float* __restrict__ b2_, const float* __restrict__ b3_,
    float* __restrict__ O0, float* __restrict__ O1,
    float* __restrict__ O2, float* __restrict__ O3) {
  __shared__ __align__(16) float As[8][128];
  __shared__ __align__(16) float Bs[8][128];
  int tid = threadIdx.x;
  int bx = blockIdx.x, by = blockIdx.y;
  int mm = bx >> 2;
  int col0 = (bx & 3) * 128;
  const float* W = mm == 0 ? W0 : mm == 1 ? W1_ : mm == 2 ? W2_ : W3_;
  const float* bias = mm == 0 ? b0 : mm == 1 ? b1_ : mm == 2 ? b2_ : b3_;
  float* O = mm == 0 ? O0 : mm == 1 ? O1 : mm == 2 ? O2 : O3;
  int tx = tid & 15, ty = tid >> 4;
  int m0 = by * 128;
  int lr = tid >> 1, lk = (tid & 1) * 4;
  const float* Ap = A + (size_t)(m0 + lr) * DD + lk;
  const float* Wp = W + (size_t)(col0 + lr) * DD + lk;
  float c[8][8] = {};
  for (int k0 = 0; k0 < DD; k0 += 8) {
    float4 av = *(const float4*)(Ap + k0);
    float4 wv = *(const float4*)(Wp + k0);
    __syncthreads();
    As[lk + 0][lr] = av.x; As[lk + 1][lr] = av.y; As[lk + 2][lr] = av.z; As[lk + 3][lr] = av.w;
    Bs[lk + 0][lr] = wv.x; Bs[lk + 1][lr] = wv.y; Bs[lk + 2][lr] = wv.z; Bs[lk + 3][lr] = wv.w;
    __syncthreads();
    #pragma unroll
    for (int k = 0; k < 8; k++) {
      float a[8], bb[8];
      *(float4*)&a[0] = *(const float4*)&As[k][ty * 8];
      *(float4*)&a[4] = *(const float4*)&As[k][ty * 8 + 4];
      *(float4*)&bb[0] = *(const float4*)&Bs[k][tx * 8];
      *(float4*)&bb[4] = *(const float4*)&Bs[k][tx * 8 + 4];
      #pragma unroll
      for (int i = 0; i < 8; i++)
        #pragma unroll
        for (int j = 0; j < 8; j++) c[i][j] += a[i] * bb[j];
    }
  }
  const float* bp = bias + col0 + tx * 8;
  for (int i = 0; i < 8; i++) {
    int row = m0 + ty * 8 + i;
    float* op = O + (size_t)row * DD + col0 + tx * 8;
    #pragma unroll
    for (int jq = 0; jq < 8; jq += 4) {
      float4 v;
      v.x = c[i][jq + 0] + bp[jq + 0];
      v.y = c[i][jq + 1] + bp[jq + 1];
      v.z = c[i][jq + 2] + bp[jq + 2];
      v.w = c[i][jq + 3] + bp[jq + 3];
      *(float4*)(op + jq) = v;
    }
  }
}

__global__ __launch_bounds__(256) void pack_kT(const float* __restrict__ Ks32,
                                               const float* __restrict__ Kc32,
                                               ushort_t* __restrict__ KsT,
                                               ushort_t* __restrict__ KcT) {
  int z = blockIdx.z;
  int b = z >> 1;
  const float* in = ((z & 1) ? Kc32 : Ks32) + (size_t)b * NN * DD;
  ushort_t* out = ((z & 1) ? KcT : KsT) + (size_t)b * NN * DD;
  int r0 = blockIdx.x * 32, c0 = blockIdx.y * 32;
  __shared__ float tile[32][33];
  int tid = threadIdx.x;
  int i = tid >> 3, j4 = (tid & 7) * 4;
  float4 v = *(const float4*)(in + (size_t)(r0 + i) * DD + c0 + j4);
  tile[i][j4] = v.x; tile[i][j4 + 1] = v.y; tile[i][j4 + 2] = v.z; tile[i][j4 + 3] = v.w;
  __syncthreads();
  ushort_t* op = out + (size_t)(c0 + i) * NN + r0 + j4;
  op[0] = f2bf(tile[j4][i]); op[1] = f2bf(tile[j4 + 1][i]);
  op[2] = f2bf(tile[j4 + 2][i]); op[3] = f2bf(tile[j4 + 3][i]);
}

__global__ __launch_bounds__(256) void pack_vh(const float* __restrict__ Vs32,
                                               const float* __restrict__ Vc32,
                                               ushort_t* __restrict__ VsH,
                                               ushort_t* __restrict__ VcH) {
  const float* src = blockIdx.y ? Vc32 : Vs32;
  ushort_t* dst = blockIdx.y ? VcH : VsH;
  size_t idx = (size_t)blockIdx.x * 1024 + threadIdx.x * 4;
  float4 v = *(const float4*)(src + idx);
  int d512 = (int)(idx & 511);
  int n = (int)((idx >> 9) & 255);
  int b = (int)(idx >> 17);
  int h = d512 >> 6, d = d512 & 63;
  ushort_t* op = dst + (((size_t)(b * 8 + h) * NN + n) * DH + d);
  op[0] = f2bf(v.x); op[1] = f2bf(v.y); op[2] = f2bf(v.z); op[3] = f2bf(v.w);
}

struct PWItem { const float* in; ushort_t* out; int C; int K; };
struct PWArgs { PWItem m[10]; };
__global__ __launch_bounds__(256) void pack_w(PWArgs a) {
  PWItem it = a.m[blockIdx.y];
  int total = it.C * (it.K >> 2);
  int e = blockIdx.x * 256 + threadIdx.x;
  if (e >= total) return;
  int kd = it.K >> 2;
  int k4 = e % kd, col = e / kd;
  float4 v = *(const float4*)(it.in + (size_t)col * it.K + k4 * 4);
  ushort4 o;
  o.x = f2bf(v.x); o.y = f2bf(v.y); o.z = f2bf(v.z); o.w = f2bf(v.w);
  *((ushort4*)it.out + (size_t)k4 * it.C + col) = o;
}

__global__ __launch_bounds__(256) void init_x(const float* __restrict__ hv0,
                                              const float* __restrict__ pe,
                                              float* __restrict__ ws,
                                              unsigned* __restrict__ flags) {
  int i = blockIdx.x * 256 + threadIdx.x;
  ws[OFF_X + i] = hv0[i] + pe[i & (DD - 1)];
  ws[OFF_U1 + i] = 0.f;
  ws[OFF_U2 + i] = 0.f;
  ws[OFF_U3 + i] = 0.f;
  ws[OFF_CT0 + i] = 0.f;
  ws[OFF_CT1 + i] = 0.f;
  if (i < 1024) flags[i] = 0u;
}

// ---------------------------------------------------------------------------
extern "C" void kernel_launch(void* const* d_in, const int* in_sizes, int n_in,
                              void* d_out, int out_size, void* d_ws, size_t ws_size,
                              hipStream_t stream) {
  const float* H_v_all = (const float*)d_in[0];
  const float* H_v0    = (const float*)d_in[1];
  const float* pe      = (const float*)d_in[2];
  const float* s_Wq = (const float*)d_in[3];
  const float* s_Wk = (const float*)d_in[4];
  const float* s_Wv = (const float*)d_in[5];
  const float* s_Wo = (const float*)d_in[6];
  const float* s_bq = (const float*)d_in[7];
  const float* s_bk = (const float*)d_in[8];
  const float* s_bv = (const float*)d_in[9];
  const float* s_bo = (const float*)d_in[10];
  const float* sa_Wq = (const float*)d_in[11];
  const float* sa_Wk = (const float*)d_in[12];
  const float* sa_Wv = (const float*)d_in[13];
  const float* sa_Wo = (const float*)d_in[14];
  const float* sa_bq = (const float*)d_in[15];
  const float* sa_bk = (const float*)d_in[16];
  const float* sa_bv = (const float*)d_in[17];
  const float* sa_bo = (const float*)d_in[18];
  const float* ca_Wq = (const float*)d_in[19];
  const float* ca_Wk = (const float*)d_in[20];
  const float* ca_Wv = (const float*)d_in[21];
  const float* ca_Wo = (const float*)d_in[22];
  const float* ca_bq = (const float*)d_in[23];
  const float* ca_bk = (const float*)d_in[24];
  const float* ca_bv = (const float*)d_in[25];
  const float* ca_bo = (const float*)d_in[26];
  const float* ln1w = (const float*)d_in[27];
  const float* ln1b = (const float*)d_in[28];
  const float* ln2w = (const float*)d_in[29];
  const float* ln2b = (const float*)d_in[30];
  const float* ln3w = (const float*)d_in[31];
  const float* ln3b = (const float*)d_in[32];
  const float* W1   = (const float*)d_in[33];
  const float* b1   = (const float*)d_in[34];
  const float* W2   = (const float*)d_in[35];
  const float* b2   = (const float*)d_in[36];
  const float* Wout = (const float*)d_in[37];
  const float* bout = (const float*)d_in[38];

  float* ws = (float*)d_ws;
  float* Ks32 = ws + OFF_KS32;
  float* Vs32 = ws + OFF_VS32;
  float* Kc32 = ws + OFF_KC32;
  float* Vc32 = ws + OFF_VC32;
  ushort_t* ub = (ushort_t*)(ws + OFF_BF);
  unsigned* flags = (unsigned*)(ws + OFF_FLG);

  hipLaunchKernelGGL(gemm_kv, dim3(16, 64), dim3(256), 0, stream,
                     H_v_all, s_Wk, s_Wv, ca_Wk, ca_Wv,
                     s_bk, s_bv, ca_bk, ca_bv, Ks32, Vs32, Kc32, Vc32);

  hipLaunchKernelGGL(pack_kT, dim3(8, 16, 64), dim3(256), 0, stream,
                     Ks32, Kc32, ub + UOFF_KST, ub + UOFF_KCT);
  hipLaunchKernelGGL(pack_vh, dim3((unsigned)(SZ_KV / 1024), 2), dim3(256), 0,
                     stream, Vs32, Vc32, ub + UOFF_VSH, ub + UOFF_VCH);

  PWArgs pw;
  pw.m[0] = {sa_Wq, ub + UOFF_W8 + 0ull * DD * DD, DD, DD};
  pw.m[1] = {sa_Wk, ub + UOFF_W8 + 1ull * DD * DD, DD, DD};
  pw.m[2] = {sa_Wv, ub + UOFF_W8 + 2ull * DD * DD, DD, DD};
  pw.m[3] = {s_Wq,  ub + UOFF_W8 + 3ull * DD * DD, DD, DD};
  pw.m[4] = {sa_Wo, ub + UOFF_W8 + 4ull * DD * DD, DD, DD};
  pw.m[5] = {s_Wo,  ub + UOFF_W8 + 5ull * DD * DD, DD, DD};
  pw.m[6] = {ca_Wq, ub + UOFF_W8 + 6ull * DD * DD, DD, DD};
  pw.m[7] = {ca_Wo, ub + UOFF_W8 + 7ull * DD * DD, DD, DD};
  pw.m[8] = {W1, ub + UOFF_W1, DF, DD};
  pw.m[9] = {W2, ub + UOFF_W2, DD, DF};
  hipLaunchKernelGGL(pack_w, dim3(1024, 10), dim3(256), 0, stream, pw);

  hipLaunchKernelGGL(init_x, dim3(64), dim3(256), 0, stream,
                     H_v0, pe, ws, flags);

  Params P;
  P.pe = pe;
  P.sa_bq = sa_bq; P.sa_bk = sa_bk; P.sa_bv = sa_bv; P.s_bq = s_bq;
  P.sa_bo = sa_bo; P.s_bo = s_bo; P.ca_bq = ca_bq; P.ca_bo = ca_bo;
  P.ln1w = ln1w; P.ln1b = ln1b; P.ln2w = ln2w; P.ln2b = ln2b;
  P.ln3w = ln3w; P.ln3b = ln3b;
  P.b1 = b1; P.b2 = b2; P.Wout = Wout; P.bout = bout;
  P.w8 = ub + UOFF_W8; P.w1b = ub + UOFF_W1; P.w2b = ub + UOFF_W2;
  P.KsT = ub + UOFF_KST; P.KcT = ub + UOFF_KCT;
  P.VsH = ub + UOFF_VSH; P.VcH = ub + UOFF_VCH;
  P.KsaB = ub + UOFF_KSA; P.VsaB = ub + UOFF_VSA;
  P.xcur = ws + OFF_X;
  P.u1 = ws + OFF_U1; P.u2 = ws + OFF_U2; P.u3 = ws + OFF_U3;
  P.ctx0 = ws + OFF_CT0; P.ctx1 = ws + OFF_CT1;
  P.out = (float*)d_out;
  P.flags = flags;

  void* kargs[] = { (void*)&P };
  hipLaunchCooperativeKernel((void*)decode_persistent, dim3(NBLK), dim3(NTHR),
                             kargs, 0, stream);
}

// Round 3
// 3064.163 us; speedup vs baseline: 1.8229x; 1.7489x over previous
//
#include <hip/hip_runtime.h>

// ---------------------------------------------------------------------------
// VehicleTrajectoryDecoder: B=32, N=256, D=512, H=8 (dh=64), T=60, DFF=2048.
// R12: R10/R11 post-mortem shows the regression vs R9 was NOT the XCD map
// (R10 stall 75us/step ~= R11 71us/step despite 2x FETCH delta) but the new
// cross-XCD atomicAdd accumulation rounds + contended counter barrier:
// device-scope RMWs serialize per cacheline at the coherence point, must
// drain before each barrier, then readers re-fetch; the arrive counter line
// was hammered by 8 fetch_adds + 8 spinners. R12 keeps the fused 4-phase
// structure and head==XCD weight partitioning but removes ALL atomics:
// each (b,h) block stores its 512-float partial to a private slab
// uXp[b][h][:] (plain agent stores, disjoint) and readers sum 8 partials
// (8 strided loads, trivial VALU). No re-zeroing needed anywhere. ctx
// partials double-buffered by t-parity -> still no E->A barrier. Barrier =
// R9's proven collector shape scoped to 8 blocks: per-batch arrive line
// (1 word/writer), collector h0 polls then writes per-spinner release words
// in a second line (1 spinner/word). 3 barriers/step. Dependency audit:
// u1p A->B, u2p B->C, u3p C->E, ctxp parity; every overwrite is >=2
// barriers downstream of its last reader. All barriers full-block.
// ---------------------------------------------------------------------------

#define NB 32
#define NN 256
#define DD 512
#define NH 8
#define DH 64
#define TT 60
#define DF 2048
#define NBLK 256
#define NTHR 512

typedef unsigned short ushort_t;

// ---- workspace layout ------------------------------------------------------
constexpr size_t SZ_KV  = (size_t)NB * NN * DD;   // 4194304
constexpr size_t SZ_ROW = (size_t)NB * DD;
constexpr size_t SZ_PAR = (size_t)NB * NH * DD;   // 131072 (partial slabs)
constexpr size_t SZ_SAB = (size_t)NB * NH * TT * DH;
constexpr size_t OFF_KS32 = 0;
constexpr size_t OFF_VS32 = SZ_KV;
constexpr size_t OFF_KC32 = 2 * SZ_KV;
constexpr size_t OFF_VC32 = 3 * SZ_KV;
constexpr size_t OFF_X    = 0;
constexpr size_t OFF_U1P  = OFF_X   + SZ_ROW;
constexpr size_t OFF_U2P  = OFF_U1P + SZ_PAR;
constexpr size_t OFF_U3P  = OFF_U2P + SZ_PAR;
constexpr size_t OFF_CTP0 = OFF_U3P + SZ_PAR;
constexpr size_t OFF_CTP1 = OFF_CTP0 + SZ_PAR;
constexpr size_t OFF_BF   = 4 * SZ_KV;
constexpr size_t UOFF_KST = 0;
constexpr size_t UOFF_KCT = SZ_KV;
constexpr size_t UOFF_VSH = 2 * SZ_KV;
constexpr size_t UOFF_VCH = 3 * SZ_KV;
constexpr size_t UOFF_KSA = 4 * SZ_KV;
constexpr size_t UOFF_VSA = UOFF_KSA + SZ_SAB;
constexpr size_t UOFF_W8  = UOFF_VSA + SZ_SAB;
constexpr size_t UOFF_W1  = UOFF_W8 + 8ull * DD * DD;
constexpr size_t UOFF_W2  = UOFF_W1 + (size_t)DD * DF;
constexpr size_t UEND     = UOFF_W2 + (size_t)DF * DD;
constexpr size_t OFF_FLG  = OFF_BF + (UEND + 1) / 2;

// ---- helpers ----------------------------------------------------------------
__device__ __forceinline__ float ldg_a(const float* p) {
  return __hip_atomic_load(p, __ATOMIC_RELAXED, __HIP_MEMORY_SCOPE_AGENT);
}
__device__ __forceinline__ void stg_a(float* p, float v) {
  __hip_atomic_store(p, v, __ATOMIC_RELAXED, __HIP_MEMORY_SCOPE_AGENT);
}
__device__ __forceinline__ float bf2f(ushort_t u) {
  return __uint_as_float(((unsigned)u) << 16);
}
__device__ __forceinline__ ushort_t f2bf(float f) {
  unsigned u = __float_as_uint(f);
  return (ushort_t)((u + 0x7FFFu + ((u >> 16) & 1u)) >> 16);
}

// ---- params ----------------------------------------------------------------
struct Params {
  const float *pe;
  const float *sa_bq, *sa_bk, *sa_bv, *s_bq, *sa_bo, *s_bo, *ca_bq, *ca_bo;
  const float *ln1w, *ln1b, *ln2w, *ln2b, *ln3w, *ln3b;
  const float *b1, *b2, *Wout, *bout;
  const ushort_t *w8, *w1b, *w2b;
  const ushort_t *KsT, *KcT, *VsH, *VcH;
  ushort_t *KsaB, *VsaB;
  float *xcur, *u1p, *u2p, *u3p, *ctp0, *ctp1;
  float *out;
  unsigned *flags;
};

// ---- per-batch 8-block collector barrier -----------------------------------
// fl = flags + b*64. Line 0 (words 0..7): arrive, one writer per word.
// Line 1 (words 32..39): release, collector writes, one spinner per word.
__device__ __forceinline__ void gbar(unsigned* fl, int tid, int h,
                                     unsigned& rnd) {
  __builtin_amdgcn_s_waitcnt(0);
  __syncthreads();
  rnd++;
  if (h == 0) {
    if (tid >= 1 && tid < 8) {
      while (__hip_atomic_load(&fl[tid], __ATOMIC_RELAXED,
                               __HIP_MEMORY_SCOPE_AGENT) < rnd)
        __builtin_amdgcn_s_sleep(1);
    }
    __syncthreads();
    if (tid >= 1 && tid < 8)
      __hip_atomic_store(&fl[32 + tid], rnd, __ATOMIC_RELAXED,
                         __HIP_MEMORY_SCOPE_AGENT);
  } else if (tid == 0) {
    __hip_atomic_store(&fl[h], rnd, __ATOMIC_RELAXED,
                       __HIP_MEMORY_SCOPE_AGENT);
    while (__hip_atomic_load(&fl[32 + h], __ATOMIC_RELAXED,
                             __HIP_MEMORY_SCOPE_AGENT) < rnd)
      __builtin_amdgcn_s_sleep(1);
  }
  __syncthreads();
}

// ---- persistent decode (256 blocks x 512 threads; 32 batches x 8 heads) ----
__global__ __launch_bounds__(512) void decode_persistent(Params P) {
  __shared__ __align__(16) float sX[2048];    // scratch
  __shared__ __align__(16) float sPart[512];
  __shared__ float sAux[64];
  __shared__ __align__(16) float xrow[512];   // persistent x (incl. pe)
  __shared__ __align__(16) float y1s[512];    // LN1 output row
  __shared__ __align__(16) float zs[512];     // LN2 output row
  int tid = threadIdx.x;
  int bid = blockIdx.x;
  int b = bid >> 3, h = bid & 7;              // XCD = bid mod 8 = h  (key!)
  int idx8 = bid;                             // (b,h) linear index
  unsigned* fl = P.flags + b * 64;
  unsigned rnd = 0;

  xrow[tid] = ldg_a(P.xcur + (size_t)b * DD + tid);
  __syncthreads();

  for (int t = 0; t < TT; t++) {
    // ==== Phase A: proj q/k/v/qs + self-attn + spatial + u1/ctx partials ====
    {
      // proj: wave w: matrix m=w>>1, k-half=w&1; lane c -> col h*64+c
      {
        int w = tid >> 6, c = tid & 63, m = w >> 1, half = w & 1;
        int col = h * DH + c;
        const ushort4* wp = (const ushort4*)(P.w8 + (size_t)m * DD * DD) + col;
        float acc = 0.f;
        #pragma unroll 8
        for (int kq = half * 64; kq < half * 64 + 64; kq++) {
          ushort4 wv = wp[(size_t)kq * DD];
          float4 xv = *(const float4*)(xrow + kq * 4);
          acc += xv.x * bf2f(wv.x) + xv.y * bf2f(wv.y) +
                 xv.z * bf2f(wv.z) + xv.w * bf2f(wv.w);
        }
        sPart[tid] = acc;
      }
      __syncthreads();
      if (tid < 256) {  // combine halves + bias; stash in sX[512..768)
        int m = tid >> 6, c = tid & 63, col = h * DH + c;
        const float* bias = (m == 0) ? P.sa_bq : (m == 1) ? P.sa_bk
                          : (m == 2) ? P.sa_bv : P.s_bq;
        float val = sPart[(2 * m) * 64 + c] + sPart[(2 * m + 1) * 64 + c]
                    + bias[col];
        sX[512 + tid] = val;
        if (m == 1) P.KsaB[((size_t)idx8 * TT + t) * DH + c] = f2bf(val);
        if (m == 2) P.VsaB[((size_t)idx8 * TT + t) * DH + c] = f2bf(val);
      }
      __syncthreads();

      // ---- self-attn over L keys (head-private bf16 cache) ----
      int L = t + 1;
      float* sQ  = sX + 512;        // q_self [64]
      float* sQs = sX + 704;        // q_spatial [64]
      float* sPb = sX + 768;        // self probs [64]
      float* sB  = sX + 1024;       // partials [512]
      if (tid < 64) {
        float sc = -1e30f;
        if (tid < L) {
          const ushort_t* kp = P.KsaB + ((size_t)idx8 * TT + tid) * DH;
          float a = 0.f;
          #pragma unroll
          for (int i = 0; i < DH; i += 4) {
            ushort4 kv = *(const ushort4*)(kp + i);
            a += sQ[i] * bf2f(kv.x) + sQ[i + 1] * bf2f(kv.y) +
                 sQ[i + 2] * bf2f(kv.z) + sQ[i + 3] * bf2f(kv.w);
          }
          sc = a * 0.125f;
        }
        float mx = sc;
        #pragma unroll
        for (int s = 32; s >= 1; s >>= 1) mx = fmaxf(mx, __shfl_xor(mx, s));
        float e = (tid < L) ? __expf(sc - mx) : 0.f;
        float s2 = e;
        #pragma unroll
        for (int s = 32; s >= 1; s >>= 1) s2 += __shfl_xor(s2, s);
        sPb[tid] = e;
        if (tid == 0) sAux[12] = 1.f / s2;
      }
      __syncthreads();
      {  // PV: 8 key-groups x 64 d
        int g = tid >> 6, d = tid & 63;
        float a2 = 0.f;
        for (int j = g; j < L; j += 8)
          a2 += sPb[j] * bf2f(P.VsaB[((size_t)idx8 * TT + j) * DH + d]);
        sB[tid] = a2;
      }
      __syncthreads();
      if (tid < 64) {   // aSA head-slice -> sX[0..64)
        float o = 0.f;
        #pragma unroll
        for (int i = 0; i < 8; i++) o += sB[i * 64 + tid];
        sX[tid] = o * sAux[12];
      }
      __syncthreads();

      // ---- spatial attn over 256 keys (d-split scores, 8-way PV) ----
      {
        int n = tid & 255, dh2 = tid >> 8;
        const ushort_t* kp = P.KsT + ((size_t)b * DD + h * DH) * NN + n;
        float a = 0.f;
        #pragma unroll 8
        for (int i = dh2 * 32; i < dh2 * 32 + 32; i++)
          a += sQs[i] * bf2f(kp[(size_t)i * NN]);
        sPart[tid] = a;
      }
      __syncthreads();
      float* sPr = sX + 1536;  // spatial probs [256]
      if (tid < 256) {  // softmax stage 1 (full-block sync'd)
        float sc = (sPart[tid] + sPart[256 + tid]) * 0.125f;
        sPr[tid] = sc;
        int w = tid >> 6, lane = tid & 63;
        float mx = sc;
        #pragma unroll
        for (int s = 32; s >= 1; s >>= 1) mx = fmaxf(mx, __shfl_xor(mx, s));
        if (lane == 0) sAux[w] = mx;
      }
      __syncthreads();
      if (tid < 256) {  // softmax stage 2
        int w = tid >> 6, lane = tid & 63;
        float mx = fmaxf(fmaxf(sAux[0], sAux[1]), fmaxf(sAux[2], sAux[3]));
        float e = __expf(sPr[tid] - mx);
        sPr[tid] = e;
        float s2 = e;
        #pragma unroll
        for (int s = 32; s >= 1; s >>= 1) s2 += __shfl_xor(s2, s);
        if (lane == 0) sAux[4 + w] = s2;
      }
      __syncthreads();
      {
        int g = tid >> 6, d = tid & 63;
        float inv = 1.f / (sAux[4] + sAux[5] + sAux[6] + sAux[7]);
        const ushort_t* vp = P.VsH + ((size_t)idx8 * NN + g * 32) * DH + d;
        float acc = 0.f;
        #pragma unroll 4
        for (int n = 0; n < 32; n++) acc += sPr[g * 32 + n] * bf2f(vp[(size_t)n * DH]);
        sB[tid] = acc * inv;
      }
      __syncthreads();
      if (tid < 64) {   // aSP head-slice -> sX[64..128)
        float o = 0.f;
        #pragma unroll
        for (int i = 0; i < 8; i++) o += sB[i * 64 + tid];
        sX[64 + tid] = o;
      }
      __syncthreads();

      // ---- u1/ctx k-chunk-h partials: row-slice gemv + disjoint store ----
      {
        float* ctp = ((t & 1) ? P.ctp1 : P.ctp0) + ((size_t)b * NH + h) * DD;
        float* u1p = P.u1p + ((size_t)b * NH + h) * DD;
        const ushort4* wpa = (const ushort4*)(P.w8 + 4ull * DD * DD) + tid;
        const ushort4* wpb = (const ushort4*)(P.w8 + 5ull * DD * DD) + tid;
        float acc1 = (h == 0) ? P.sa_bo[tid] + xrow[tid] : 0.f;
        float acc2 = (h == 0) ? P.s_bo[tid] : 0.f;
        #pragma unroll 8
        for (int j = 0; j < 16; j++) {
          int k4 = h * 16 + j;
          ushort4 wv = wpa[(size_t)k4 * DD];
          float4 xv = *(const float4*)(sX + j * 4);
          acc1 += xv.x * bf2f(wv.x) + xv.y * bf2f(wv.y) +
                  xv.z * bf2f(wv.z) + xv.w * bf2f(wv.w);
          ushort4 wv2 = wpb[(size_t)k4 * DD];
          float4 xv2 = *(const float4*)(sX + 64 + j * 4);
          acc2 += xv2.x * bf2f(wv2.x) + xv2.y * bf2f(wv2.y) +
                  xv2.z * bf2f(wv2.z) + xv2.w * bf2f(wv2.w);
        }
        stg_a(&u1p[tid], acc1);
        stg_a(&ctp[tid], acc2);
      }
    }
    gbar(fl, tid, h, rnd);

    // ==== Phase B: sum u1p -> LN1 -> y1s ; qc ; cross-attn ; u2 partial =====
    {
      float u = 0.f;
      {
        const float* pp = P.u1p + (size_t)b * NH * DD + tid;
        #pragma unroll
        for (int i = 0; i < 8; i++) u += ldg_a(pp + i * DD);
      }
      {
        int w = tid >> 6, lane = tid & 63;
        float s = u, q2 = u * u;
        #pragma unroll
        for (int m = 32; m >= 1; m >>= 1) { s += __shfl_xor(s, m); q2 += __shfl_xor(q2, m); }
        if (lane == 0) { sAux[w] = s; sAux[8 + w] = q2; }
      }
      __syncthreads();
      {
        float ss = 0.f, qq = 0.f;
        #pragma unroll
        for (int i = 0; i < 8; i++) { ss += sAux[i]; qq += sAux[8 + i]; }
        float mean = ss * (1.f / 512.f);
        float inv = rsqrtf(qq * (1.f / 512.f) - mean * mean + 1e-5f);
        y1s[tid] = (u - mean) * inv * P.ln1w[tid] + P.ln1b[tid];
      }
      __syncthreads();
      {  // qc: 8 k-chunks of 64
        int c = tid & 63, w = tid >> 6, col = h * DH + c;
        const ushort4* wp = (const ushort4*)(P.w8 + 6ull * DD * DD) + col;
        float acc = 0.f;
        #pragma unroll 8
        for (int kq = w * 16; kq < w * 16 + 16; kq++) {
          ushort4 wv = wp[(size_t)kq * DD];
          float4 xv = *(const float4*)(y1s + kq * 4);
          acc += xv.x * bf2f(wv.x) + xv.y * bf2f(wv.y) +
                 xv.z * bf2f(wv.z) + xv.w * bf2f(wv.w);
        }
        sPart[tid] = acc;
      }
      __syncthreads();
      float* sQc = sX + 512;
      if (tid < 64) {
        float acc = 0.f;
        #pragma unroll
        for (int i = 0; i < 8; i++) acc += sPart[i * 64 + tid];
        sQc[tid] = acc + P.ca_bq[h * DH + tid];
      }
      __syncthreads();
      // cross-attn scores (d-split)
      {
        int n = tid & 255, dh2 = tid >> 8;
        const ushort_t* kp = P.KcT + ((size_t)b * DD + h * DH) * NN + n;
        float a = 0.f;
        #pragma unroll 8
        for (int i = dh2 * 32; i < dh2 * 32 + 32; i++)
          a += sQc[i] * bf2f(kp[(size_t)i * NN]);
        sPart[tid] = a;
      }
      __syncthreads();
      float* sPr = sX + 1536;
      if (tid < 256) {  // softmax stage 1
        float sc = (sPart[tid] + sPart[256 + tid]) * 0.125f;
        sPr[tid] = sc;
        int w = tid >> 6, lane = tid & 63;
        float mx = sc;
        #pragma unroll
        for (int s = 32; s >= 1; s >>= 1) mx = fmaxf(mx, __shfl_xor(mx, s));
        if (lane == 0) sAux[w] = mx;
      }
      __syncthreads();
      if (tid < 256) {  // softmax stage 2
        int w = tid >> 6, lane = tid & 63;
        float mx = fmaxf(fmaxf(sAux[0], sAux[1]), fmaxf(sAux[2], sAux[3]));
        float e = __expf(sPr[tid] - mx);
        sPr[tid] = e;
        float s2 = e;
        #pragma unroll
        for (int s = 32; s >= 1; s >>= 1) s2 += __shfl_xor(s2, s);
        if (lane == 0) sAux[4 + w] = s2;
      }
      __syncthreads();
      float* sB = sX + 1024;
      {
        int g = tid >> 6, d = tid & 63;
        float inv = 1.f / (sAux[4] + sAux[5] + sAux[6] + sAux[7]);
        const ushort_t* vp = P.VcH + ((size_t)idx8 * NN + g * 32) * DH + d;
        float acc = 0.f;
        #pragma unroll 4
        for (int n = 0; n < 32; n++) acc += sPr[g * 32 + n] * bf2f(vp[(size_t)n * DH]);
        sB[tid] = acc * inv;
      }
      __syncthreads();
      if (tid < 64) {   // aCA head-slice -> sX[0..64)
        float o = 0.f;
        #pragma unroll
        for (int i = 0; i < 8; i++) o += sB[i * 64 + tid];
        sX[tid] = o;
      }
      __syncthreads();
      {  // u2 k-chunk-h partial -> disjoint store (h0 adds bias + y1 resid)
        const ushort4* wp = (const ushort4*)(P.w8 + 7ull * DD * DD) + tid;
        float acc = (h == 0) ? P.ca_bo[tid] + y1s[tid] : 0.f;
        #pragma unroll 8
        for (int j = 0; j < 16; j++) {
          int k4 = h * 16 + j;
          ushort4 wv = wp[(size_t)k4 * DD];
          float4 xv = *(const float4*)(sX + j * 4);
          acc += xv.x * bf2f(wv.x) + xv.y * bf2f(wv.y) +
                 xv.z * bf2f(wv.z) + xv.w * bf2f(wv.w);
        }
        stg_a(&P.u2p[((size_t)b * NH + h) * DD + tid], acc);
      }
    }
    gbar(fl, tid, h, rnd);

    // ==== Phase C: sum u2p -> LN2 -> zs ; FFN1 slice ; fused FFN2 partial ===
    {
      float v = 0.f;
      {
        const float* pp = P.u2p + (size_t)b * NH * DD + tid;
        #pragma unroll
        for (int i = 0; i < 8; i++) v += ldg_a(pp + i * DD);
      }
      {
        int w = tid >> 6, lane = tid & 63;
        float s = v, q2 = v * v;
        #pragma unroll
        for (int m = 32; m >= 1; m >>= 1) { s += __shfl_xor(s, m); q2 += __shfl_xor(q2, m); }
        if (lane == 0) { sAux[w] = s; sAux[8 + w] = q2; }
      }
      __syncthreads();
      {
        float ss = 0.f, qq = 0.f;
        #pragma unroll
        for (int i = 0; i < 8; i++) { ss += sAux[i]; qq += sAux[8 + i]; }
        float mean = ss * (1.f / 512.f);
        float inv = rsqrtf(qq * (1.f / 512.f) - mean * mean + 1e-5f);
        zs[tid] = (v - mean) * inv * P.ln2w[tid] + P.ln2b[tid];
      }
      __syncthreads();
      {  // FFN1: cols h*256..h*256+255, k split in 2 halves
        int c = tid & 255, half = tid >> 8, col = h * 256 + c;
        const ushort4* wp = (const ushort4*)P.w1b + col;
        float acc = 0.f;
        #pragma unroll 8
        for (int kq = half * 64; kq < half * 64 + 64; kq++) {
          ushort4 wv = wp[(size_t)kq * DF];
          float4 xv = *(const float4*)(zs + kq * 4);
          acc += xv.x * bf2f(wv.x) + xv.y * bf2f(wv.y) +
                 xv.z * bf2f(wv.z) + xv.w * bf2f(wv.w);
        }
        sPart[tid] = acc;
      }
      __syncthreads();
      float* hh = sX;  // relu hidden slice [256]
      if (tid < 256)
        hh[tid] = fmaxf(sPart[tid] + sPart[256 + tid] + P.b1[h * 256 + tid], 0.f);
      __syncthreads();
      {  // fused FFN2: u3 partial over k-chunk h (W2 rows h*256..h*256+255)
        const ushort4* wp = (const ushort4*)P.w2b + tid;
        float acc = (h == 0) ? zs[tid] + P.b2[tid] : 0.f;
        #pragma unroll 8
        for (int j = 0; j < 64; j++) {
          int k4 = h * 64 + j;
          ushort4 wv = wp[(size_t)k4 * DD];
          float4 xv = *(const float4*)(hh + j * 4);
          acc += xv.x * bf2f(wv.x) + xv.y * bf2f(wv.y) +
                 xv.z * bf2f(wv.z) + xv.w * bf2f(wv.w);
        }
        stg_a(&P.u3p[((size_t)b * NH + h) * DD + tid], acc);
      }
    }
    gbar(fl, tid, h, rnd);

    // ==== Phase E: sum u3p -> LN3 ; +ctx(sum) ; xrow=nxt+pe ; h0: out =======
    {
      float u = 0.f, ctxv = 0.f;
      {
        const float* pp = P.u3p + (size_t)b * NH * DD + tid;
        const float* cp = ((t & 1) ? P.ctp1 : P.ctp0) + (size_t)b * NH * DD + tid;
        #pragma unroll
        for (int i = 0; i < 8; i++) { u += ldg_a(pp + i * DD); ctxv += ldg_a(cp + i * DD); }
      }
      {
        int w = tid >> 6, lane = tid & 63;
        float s = u, q2 = u * u;
        #pragma unroll
        for (int m = 32; m >= 1; m >>= 1) { s += __shfl_xor(s, m); q2 += __shfl_xor(q2, m); }
        if (lane == 0) { sAux[w] = s; sAux[8 + w] = q2; }
      }
      __syncthreads();
      float ss = 0.f, qq = 0.f;
      #pragma unroll
      for (int i = 0; i < 8; i++) { ss += sAux[i]; qq += sAux[8 + i]; }
      float mean = ss * (1.f / 512.f);
      float inv = rsqrtf(qq * (1.f / 512.f) - mean * mean + 1e-5f);
      float nxt = (u - mean) * inv * P.ln3w[tid] + P.ln3b[tid] + ctxv;
      float p = (t < TT - 1) ? P.pe[(size_t)(t + 1) * DD + tid] : 0.f;
      if (h == 0) sX[tid] = nxt;
      __syncthreads();
      xrow[tid] = nxt + p;
      if (h == 0) {   // block-uniform branch: inner barrier legal
        {
          int c = tid >> 8, l = tid & 255;
          float a = sX[l] * P.Wout[(size_t)c * DD + l] +
                    sX[l + 256] * P.Wout[(size_t)c * DD + l + 256];
          #pragma unroll
          for (int m = 32; m >= 1; m >>= 1) a += __shfl_xor(a, m);
          if ((tid & 63) == 0) sAux[16 + (tid >> 6)] = a;
        }
        __syncthreads();
        if (tid == 0)
          P.out[((size_t)b * TT + t) * 2 + 0] =
              sAux[16] + sAux[17] + sAux[18] + sAux[19] + P.bout[0];
        if (tid == 256)
          P.out[((size_t)b * TT + t) * 2 + 1] =
              sAux[20] + sAux[21] + sAux[22] + sAux[23] + P.bout[1];
      }
      __syncthreads();  // xrow/sAux stable before next Phase A
    }
    // no barrier: A(t+1) writes only block-private state or the opposite
    // ctx parity buffer; u1p overwrite is >=2 barriers past its readers.
  }
}

// ---- precompute kernels -----------------------------------------------------
__global__ __launch_bounds__(256) void gemm_kv(
    const float* __restrict__ A,
    const float* __restrict__ W0, const float* __restrict__ W1_,
    const float* __restrict__ W2_, const float* __restrict__ W3_,
    const float* __restrict__ b0, const float* __restrict__ b1_,
    const float* __restrict__ b2_, const float* __restrict__ b3_,
    float* __restrict__ O0, float* __restrict__ O1,
    float* __restrict__ O2, float* __restrict__ O3) {
  __shared__ __align__(16) float As[8][128];
  __shared__ __align__(16) float Bs[8][128];
  int tid = threadIdx.x;
  int bx = blockIdx.x, by = blockIdx.y;
  int mm = bx >> 2;
  int col0 = (bx & 3) * 128;
  const float* W = mm == 0 ? W0 : mm == 1 ? W1_ : mm == 2 ? W2_ : W3_;
  const float* bias = mm == 0 ? b0 : mm == 1 ? b1_ : mm == 2 ? b2_ : b3_;
  float* O = mm == 0 ? O0 : mm == 1 ? O1 : mm == 2 ? O2 : O3;
  int tx = tid & 15, ty = tid >> 4;
  int m0 = by * 128;
  int lr = tid >> 1, lk = (tid & 1) * 4;
  const float* Ap = A + (size_t)(m0 + lr) * DD + lk;
  const float* Wp = W + (size_t)(col0 + lr) * DD + lk;
  float c[8][8] = {};
  for (int k0 = 0; k0 < DD; k0 += 8) {
    float4 av = *(const float4*)(Ap + k0);
    float4 wv = *(const float4*)(Wp + k0);
    __syncthreads();
    As[lk + 0][lr] = av.x; As[lk + 1][lr] = av.y; As[lk + 2][lr] = av.z; As[lk + 3][lr] = av.w;
    Bs[lk + 0][lr] = wv.x; Bs[lk + 1][lr] = wv.y; Bs[lk + 2][lr] = wv.z; Bs[lk + 3][lr] = wv.w;
    __syncthreads();
    #pragma unroll
    for (int k = 0; k < 8; k++) {
      float a[8], bb[8];
      *(float4*)&a[0] = *(const float4*)&As[k][ty * 8];
      *(float4*)&a[4] = *(const float4*)&As[k][ty * 8 + 4];
      *(float4*)&bb[0] = *(const float4*)&Bs[k][tx * 8];
      *(float4*)&bb[4] = *(const float4*)&Bs[k][tx * 8 + 4];
      #pragma unroll
      for (int i = 0; i < 8; i++)
        #pragma unroll
        for (int j = 0; j < 8; j++) c[i][j] += a[i] * bb[j];
    }
  }
  const float* bp = bias + col0 + tx * 8;
  for (int i = 0; i < 8; i++) {
    int row = m0 + ty * 8 + i;
    float* op = O + (size_t)row * DD + col0 + tx * 8;
    #pragma unroll
    for (int jq = 0; jq < 8; jq += 4) {
      float4 v;
      v.x = c[i][jq + 0] + bp[jq + 0];
      v.y = c[i][jq + 1] + bp[jq + 1];
      v.z = c[i][jq + 2] + bp[jq + 2];
      v.w = c[i][jq + 3] + bp[jq + 3];
      *(float4*)(op + jq) = v;
    }
  }
}

__global__ __launch_bounds__(256) void pack_kT(const float* __restrict__ Ks32,
                                               const float* __restrict__ Kc32,
                                               ushort_t* __restrict__ KsT,
                                               ushort_t* __restrict__ KcT) {
  int z = blockIdx.z;
  int b = z >> 1;
  const float* in = ((z & 1) ? Kc32 : Ks32) + (size_t)b * NN * DD;
  ushort_t* out = ((z & 1) ? KcT : KsT) + (size_t)b * NN * DD;
  int r0 = blockIdx.x * 32, c0 = blockIdx.y * 32;
  __shared__ float tile[32][33];
  int tid = threadIdx.x;
  int i = tid >> 3, j4 = (tid & 7) * 4;
  float4 v = *(const float4*)(in + (size_t)(r0 + i) * DD + c0 + j4);
  tile[i][j4] = v.x; tile[i][j4 + 1] = v.y; tile[i][j4 + 2] = v.z; tile[i][j4 + 3] = v.w;
  __syncthreads();
  ushort_t* op = out + (size_t)(c0 + i) * NN + r0 + j4;
  op[0] = f2bf(tile[j4][i]); op[1] = f2bf(tile[j4 + 1][i]);
  op[2] = f2bf(tile[j4 + 2][i]); op[3] = f2bf(tile[j4 + 3][i]);
}

__global__ __launch_bounds__(256) void pack_vh(const float* __restrict__ Vs32,
                                               const float* __restrict__ Vc32,
                                               ushort_t* __restrict__ VsH,
                                               ushort_t* __restrict__ VcH) {
  const float* src = blockIdx.y ? Vc32 : Vs32;
  ushort_t* dst = blockIdx.y ? VcH : VsH;
  size_t idx = (size_t)blockIdx.x * 1024 + threadIdx.x * 4;
  float4 v = *(const float4*)(src + idx);
  int d512 = (int)(idx & 511);
  int n = (int)((idx >> 9) & 255);
  int b = (int)(idx >> 17);
  int h = d512 >> 6, d = d512 & 63;
  ushort_t* op = dst + (((size_t)(b * 8 + h) * NN + n) * DH + d);
  op[0] = f2bf(v.x); op[1] = f2bf(v.y); op[2] = f2bf(v.z); op[3] = f2bf(v.w);
}

struct PWItem { const float* in; ushort_t* out; int C; int K; };
struct PWArgs { PWItem m[10]; };
__global__ __launch_bounds__(256) void pack_w(PWArgs a) {
  PWItem it = a.m[blockIdx.y];
  int total = it.C * (it.K >> 2);
  int e = blockIdx.x * 256 + threadIdx.x;
  if (e >= total) return;
  int kd = it.K >> 2;
  int k4 = e % kd, col = e / kd;
  float4 v = *(const float4*)(it.in + (size_t)col * it.K + k4 * 4);
  ushort4 o;
  o.x = f2bf(v.x); o.y = f2bf(v.y); o.z = f2bf(v.z); o.w = f2bf(v.w);
  *((ushort4*)it.out + (size_t)k4 * it.C + col) = o;
}

__global__ __launch_bounds__(256) void init_x(const float* __restrict__ hv0,
                                              const float* __restrict__ pe,
                                              float* __restrict__ ws,
                                              unsigned* __restrict__ flags) {
  int i = blockIdx.x * 256 + threadIdx.x;
  ws[OFF_X + i] = hv0[i] + pe[i & (DD - 1)];
  if (i < 2048) flags[i] = 0u;
}

// ---------------------------------------------------------------------------
extern "C" void kernel_launch(void* const* d_in, const int* in_sizes, int n_in,
                              void* d_out, int out_size, void* d_ws, size_t ws_size,
                              hipStream_t stream) {
  const float* H_v_all = (const float*)d_in[0];
  const float* H_v0    = (const float*)d_in[1];
  const float* pe      = (const float*)d_in[2];
  const float* s_Wq = (const float*)d_in[3];
  const float* s_Wk = (const float*)d_in[4];
  const float* s_Wv = (const float*)d_in[5];
  const float* s_Wo = (const float*)d_in[6];
  const float* s_bq = (const float*)d_in[7];
  const float* s_bk = (const float*)d_in[8];
  const float* s_bv = (const float*)d_in[9];
  const float* s_bo = (const float*)d_in[10];
  const float* sa_Wq = (const float*)d_in[11];
  const float* sa_Wk = (const float*)d_in[12];
  const float* sa_Wv = (const float*)d_in[13];
  const float* sa_Wo = (const float*)d_in[14];
  const float* sa_bq = (const float*)d_in[15];
  const float* sa_bk = (const float*)d_in[16];
  const float* sa_bv = (const float*)d_in[17];
  const float* sa_bo = (const float*)d_in[18];
  const float* ca_Wq = (const float*)d_in[19];
  const float* ca_Wk = (const float*)d_in[20];
  const float* ca_Wv = (const float*)d_in[21];
  const float* ca_Wo = (const float*)d_in[22];
  const float* ca_bq = (const float*)d_in[23];
  const float* ca_bk = (const float*)d_in[24];
  const float* ca_bv = (const float*)d_in[25];
  const float* ca_bo = (const float*)d_in[26];
  const float* ln1w = (const float*)d_in[27];
  const float* ln1b = (const float*)d_in[28];
  const float* ln2w = (const float*)d_in[29];
  const float* ln2b = (const float*)d_in[30];
  const float* ln3w = (const float*)d_in[31];
  const float* ln3b = (const float*)d_in[32];
  const float* W1   = (const float*)d_in[33];
  const float* b1   = (const float*)d_in[34];
  const float* W2   = (const float*)d_in[35];
  const float* b2   = (const float*)d_in[36];
  const float* Wout = (const float*)d_in[37];
  const float* bout = (const float*)d_in[38];

  float* ws = (float*)d_ws;
  float* Ks32 = ws + OFF_KS32;
  float* Vs32 = ws + OFF_VS32;
  float* Kc32 = ws + OFF_KC32;
  float* Vc32 = ws + OFF_VC32;
  ushort_t* ub = (ushort_t*)(ws + OFF_BF);
  unsigned* flags = (unsigned*)(ws + OFF_FLG);

  hipLaunchKernelGGL(gemm_kv, dim3(16, 64), dim3(256), 0, stream,
                     H_v_all, s_Wk, s_Wv, ca_Wk, ca_Wv,
                     s_bk, s_bv, ca_bk, ca_bv, Ks32, Vs32, Kc32, Vc32);

  hipLaunchKernelGGL(pack_kT, dim3(8, 16, 64), dim3(256), 0, stream,
                     Ks32, Kc32, ub + UOFF_KST, ub + UOFF_KCT);
  hipLaunchKernelGGL(pack_vh, dim3((unsigned)(SZ_KV / 1024), 2), dim3(256), 0,
                     stream, Vs32, Vc32, ub + UOFF_VSH, ub + UOFF_VCH);

  PWArgs pw;
  pw.m[0] = {sa_Wq, ub + UOFF_W8 + 0ull * DD * DD, DD, DD};
  pw.m[1] = {sa_Wk, ub + UOFF_W8 + 1ull * DD * DD, DD, DD};
  pw.m[2] = {sa_Wv, ub + UOFF_W8 + 2ull * DD * DD, DD, DD};
  pw.m[3] = {s_Wq,  ub + UOFF_W8 + 3ull * DD * DD, DD, DD};
  pw.m[4] = {sa_Wo, ub + UOFF_W8 + 4ull * DD * DD, DD, DD};
  pw.m[5] = {s_Wo,  ub + UOFF_W8 + 5ull * DD * DD, DD, DD};
  pw.m[6] = {ca_Wq, ub + UOFF_W8 + 6ull * DD * DD, DD, DD};
  pw.m[7] = {ca_Wo, ub + UOFF_W8 + 7ull * DD * DD, DD, DD};
  pw.m[8] = {W1, ub + UOFF_W1, DF, DD};
  pw.m[9] = {W2, ub + UOFF_W2, DD, DF};
  hipLaunchKernelGGL(pack_w, dim3(1024, 10), dim3(256), 0, stream, pw);

  hipLaunchKernelGGL(init_x, dim3(64), dim3(256), 0, stream,
                     H_v0, pe, ws, flags);

  Params P;
  P.pe = pe;
  P.sa_bq = sa_bq; P.sa_bk = sa_bk; P.sa_bv = sa_bv; P.s_bq = s_bq;
  P.sa_bo = sa_bo; P.s_bo = s_bo; P.ca_bq = ca_bq; P.ca_bo = ca_bo;
  P.ln1w = ln1w; P.ln1b = ln1b; P.ln2w = ln2w; P.ln2b = ln2b;
  P.ln3w = ln3w; P.ln3b = ln3b;
  P.b1 = b1; P.b2 = b2; P.Wout = Wout; P.bout = bout;
  P.w8 = ub + UOFF_W8; P.w1b = ub + UOFF_W1; P.w2b = ub + UOFF_W2;
  P.KsT = ub + UOFF_KST; P.KcT = ub + UOFF_KCT;
  P.VsH = ub + UOFF_VSH; P.VcH = ub + UOFF_VCH;
  P.KsaB = ub + UOFF_KSA; P.VsaB = ub + UOFF_VSA;
  P.xcur = ws + OFF_X;
  P.u1p = ws + OFF_U1P; P.u2p = ws + OFF_U2P; P.u3p = ws + OFF_U3P;
  P.ctp0 = ws + OFF_CTP0; P.ctp1 = ws + OFF_CTP1;
  P.out = (float*)d_out;
  P.flags = flags;

  void* kargs[] = { (void*)&P };
  hipLaunchCooperativeKernel((void*)decode_persistent, dim3(NBLK), dim3(NTHR),
                             kargs, 0, stream);
}

// Round 4
// 2656.407 us; speedup vs baseline: 2.1028x; 1.1535x over previous
//
#include <hip/hip_runtime.h>

// ---------------------------------------------------------------------------
// VehicleTrajectoryDecoder: B=32, N=256, D=512, H=8 (dh=64), T=60, DFF=2048.
// R13: R12 (2718us dispatch) confirmed: partial-exchange via disjoint slabs +
// collector barrier fixed the R10/R11 RMW stall. Remaining 45us/step =
// ~12 VALU + ~10 barrier + ~8 exchange/KV latency + syncs. R13 attacks the
// first two:
//  (1) f16 + v_dot2_f32_f16 everywhere: weights/KV/self-attn cache stored as
//      f16 (better mantissa than bf16); activations packed to f16 pairs in
//      LDS once per phase (cvt_pkrtz); all gemv/score inner loops become
//      fdot2 (1 VALU per 2 elements vs 2 per element). K^T repacked as
//      d-pair words so score loops are 16 dot2s. PV kept scalar (rank-1).
//  (2) symmetric 1-RTT barrier: lane h stores arrive word; wave0 of EVERY
//      block polls all 8 words of the line with __any (no collector, no
//      release line) -- halves per-barrier latency vs R12's 2-RTT shape.
// Structure (4 fused phases, 3 barriers/step, head==XCD, slab exchange,
// xrow in LDS) unchanged from R12.
// ---------------------------------------------------------------------------

#define NB 32
#define NN 256
#define DD 512
#define NH 8
#define DH 64
#define TT 60
#define DF 2048
#define NBLK 256
#define NTHR 512

typedef unsigned short ushort_t;
typedef _Float16 half2v __attribute__((ext_vector_type(2)));

// ---- workspace layout ------------------------------------------------------
constexpr size_t SZ_KV  = (size_t)NB * NN * DD;   // 4194304
constexpr size_t SZ_ROW = (size_t)NB * DD;
constexpr size_t SZ_PAR = (size_t)NB * NH * DD;   // 131072 (partial slabs)
constexpr size_t SZ_SAB = (size_t)NB * NH * TT * DH;
constexpr size_t OFF_KS32 = 0;
constexpr size_t OFF_VS32 = SZ_KV;
constexpr size_t OFF_KC32 = 2 * SZ_KV;
constexpr size_t OFF_VC32 = 3 * SZ_KV;
constexpr size_t OFF_X    = 0;
constexpr size_t OFF_U1P  = OFF_X   + SZ_ROW;
constexpr size_t OFF_U2P  = OFF_U1P + SZ_PAR;
constexpr size_t OFF_U3P  = OFF_U2P + SZ_PAR;
constexpr size_t OFF_CTP0 = OFF_U3P + SZ_PAR;
constexpr size_t OFF_CTP1 = OFF_CTP0 + SZ_PAR;
constexpr size_t OFF_BF   = 4 * SZ_KV;
constexpr size_t UOFF_KST = 0;
constexpr size_t UOFF_KCT = SZ_KV;
constexpr size_t UOFF_VSH = 2 * SZ_KV;
constexpr size_t UOFF_VCH = 3 * SZ_KV;
constexpr size_t UOFF_KSA = 4 * SZ_KV;
constexpr size_t UOFF_VSA = UOFF_KSA + SZ_SAB;
constexpr size_t UOFF_W8  = UOFF_VSA + SZ_SAB;
constexpr size_t UOFF_W1  = UOFF_W8 + 8ull * DD * DD;
constexpr size_t UOFF_W2  = UOFF_W1 + (size_t)DD * DF;
constexpr size_t UEND     = UOFF_W2 + (size_t)DF * DD;
constexpr size_t OFF_FLG  = OFF_BF + (UEND + 1) / 2;

// ---- helpers ----------------------------------------------------------------
__device__ __forceinline__ float ldg_a(const float* p) {
  return __hip_atomic_load(p, __ATOMIC_RELAXED, __HIP_MEMORY_SCOPE_AGENT);
}
__device__ __forceinline__ void stg_a(float* p, float v) {
  __hip_atomic_store(p, v, __ATOMIC_RELAXED, __HIP_MEMORY_SCOPE_AGENT);
}
__device__ __forceinline__ unsigned f2pk(float a, float b) {
  return __builtin_bit_cast(unsigned, __builtin_amdgcn_cvt_pkrtz(a, b));
}
__device__ __forceinline__ ushort_t f2h(float a) {
  return (ushort_t)(f2pk(a, 0.f) & 0xffffu);
}
__device__ __forceinline__ float h2f(ushort_t u) {
  return (float)__builtin_bit_cast(_Float16, u);
}
__device__ __forceinline__ float fdot2u(unsigned a, unsigned b, float c) {
  return __builtin_amdgcn_fdot2(__builtin_bit_cast(half2v, a),
                                __builtin_bit_cast(half2v, b), c, false);
}

// ---- params ----------------------------------------------------------------
struct Params {
  const float *pe;
  const float *sa_bq, *sa_bk, *sa_bv, *s_bq, *sa_bo, *s_bo, *ca_bq, *ca_bo;
  const float *ln1w, *ln1b, *ln2w, *ln2b, *ln3w, *ln3b;
  const float *b1, *b2, *Wout, *bout;
  const ushort_t *w8, *w1b, *w2b;
  const ushort_t *KsT, *KcT, *VsH, *VcH;
  ushort_t *KsaB, *VsaB;
  float *xcur, *u1p, *u2p, *u3p, *ctp0, *ctp1;
  float *out;
  unsigned *flags;
};

// ---- symmetric per-batch 8-block barrier (1 RTT) ---------------------------
// fl = flags + b*64. Words 0..7: arrive, one writer per word (lane h of the
// owning block). Every block's wave0 polls all 8 words (one 32B span).
__device__ __forceinline__ void gbar(unsigned* fl, int tid, int h,
                                     unsigned& rnd) {
  __builtin_amdgcn_s_waitcnt(0);
  __syncthreads();
  rnd++;
  if (tid < 64) {
    if (tid == h)
      __hip_atomic_store(&fl[h], rnd, __ATOMIC_RELAXED,
                         __HIP_MEMORY_SCOPE_AGENT);
    bool wait = true;
    while (wait) {
      unsigned v = rnd;
      if (tid < 8)
        v = __hip_atomic_load(&fl[tid], __ATOMIC_RELAXED,
                              __HIP_MEMORY_SCOPE_AGENT);
      wait = __any(v < rnd);
    }
  }
  __syncthreads();
}

// ---- persistent decode (256 blocks x 512 threads; 32 batches x 8 heads) ----
__global__ __launch_bounds__(512) void decode_persistent(Params P) {
  __shared__ __align__(16) float sX[2048];    // scratch
  __shared__ __align__(16) float sPart[512];
  __shared__ float sAux[64];
  __shared__ __align__(16) float xrow[512];   // persistent x (incl. pe)
  __shared__ __align__(16) float y1s[512];    // LN1 output row
  __shared__ __align__(16) float zs[512];     // LN2 output row
  __shared__ __align__(16) unsigned xh[256];  // xrow packed f16 pairs
  __shared__ __align__(16) unsigned ph[512];  // packed scratch (per-phase)
  int tid = threadIdx.x;
  int bid = blockIdx.x;
  int b = bid >> 3, h = bid & 7;              // XCD = bid mod 8 = h  (key!)
  int idx8 = bid;                             // (b,h) linear index
  unsigned* fl = P.flags + b * 64;
  unsigned rnd = 0;

  xrow[tid] = ldg_a(P.xcur + (size_t)b * DD + tid);
  __syncthreads();
  if (tid < 256) xh[tid] = f2pk(xrow[2 * tid], xrow[2 * tid + 1]);
  __syncthreads();

  for (int t = 0; t < TT; t++) {
    // ==== Phase A: proj q/k/v/qs + self-attn + spatial + u1/ctx partials ====
    {
      // proj: wave w: matrix m=w>>1, k-half=w&1; lane c -> col h*64+c
      {
        int w = tid >> 6, c = tid & 63, m = w >> 1, half = w & 1;
        int col = h * DH + c;
        const uint2* wp = (const uint2*)(P.w8 + (size_t)m * DD * DD) + col;
        float acc = 0.f;
        #pragma unroll 8
        for (int kq = half * 64; kq < half * 64 + 64; kq++) {
          uint2 wv = wp[(size_t)kq * DD];
          uint2 xv = *(const uint2*)&xh[kq * 2];
          acc = fdot2u(wv.x, xv.x, acc);
          acc = fdot2u(wv.y, xv.y, acc);
        }
        sPart[tid] = acc;
      }
      __syncthreads();
      if (tid < 256) {  // combine halves + bias; stash in sX[512..768)
        int m = tid >> 6, c = tid & 63, col = h * DH + c;
        const float* bias = (m == 0) ? P.sa_bq : (m == 1) ? P.sa_bk
                          : (m == 2) ? P.sa_bv : P.s_bq;
        float val = sPart[(2 * m) * 64 + c] + sPart[(2 * m + 1) * 64 + c]
                    + bias[col];
        sX[512 + tid] = val;
        if (m == 1) P.KsaB[((size_t)idx8 * TT + t) * DH + c] = f2h(val);
        if (m == 2) P.VsaB[((size_t)idx8 * TT + t) * DH + c] = f2h(val);
      }
      __syncthreads();

      // ---- self-attn over L keys (head-private f16 cache) ----
      int L = t + 1;
      float* sQ  = sX + 512;        // q_self [64]
      float* sQs = sX + 704;        // q_spatial [64]
      float* sPb = sX + 768;        // self probs [64]
      float* sB  = sX + 1024;       // partials [512]
      if (tid < 64) {
        float sc = -1e30f;
        if (tid < L) {
          const ushort_t* kp = P.KsaB + ((size_t)idx8 * TT + tid) * DH;
          float a = 0.f;
          #pragma unroll
          for (int i = 0; i < DH; i += 4) {
            ushort4 kv = *(const ushort4*)(kp + i);
            a += sQ[i] * h2f(kv.x) + sQ[i + 1] * h2f(kv.y) +
                 sQ[i + 2] * h2f(kv.z) + sQ[i + 3] * h2f(kv.w);
          }
          sc = a * 0.125f;
        }
        float mx = sc;
        #pragma unroll
        for (int s = 32; s >= 1; s >>= 1) mx = fmaxf(mx, __shfl_xor(mx, s));
        float e = (tid < L) ? __expf(sc - mx) : 0.f;
        float s2 = e;
        #pragma unroll
        for (int s = 32; s >= 1; s >>= 1) s2 += __shfl_xor(s2, s);
        sPb[tid] = e;
        if (tid == 0) sAux[12] = 1.f / s2;
      } else if (tid < 96) {   // pack q_spatial pairs -> ph[0..32)
        int i = tid - 64;
        ph[i] = f2pk(sQs[2 * i], sQs[2 * i + 1]);
      }
      __syncthreads();
      {  // PV: 8 key-groups x 64 d
        int g = tid >> 6, d = tid & 63;
        float a2 = 0.f;
        for (int j = g; j < L; j += 8)
          a2 += sPb[j] * h2f(P.VsaB[((size_t)idx8 * TT + j) * DH + d]);
        sB[tid] = a2;
      }
      __syncthreads();
      if (tid < 64) {   // aSA head-slice -> sX[0..64)
        float o = 0.f;
        #pragma unroll
        for (int i = 0; i < 8; i++) o += sB[i * 64 + tid];
        sX[tid] = o * sAux[12];
      }
      __syncthreads();

      // ---- spatial attn over 256 keys (d-pair dot2 scores, 8-way PV) ----
      {
        int n = tid & 255, dh2 = tid >> 8;
        const unsigned* kp = (const unsigned*)P.KsT +
                             (((size_t)b * DD + h * DH) >> 1) * NN + n;
        float a = 0.f;
        #pragma unroll 8
        for (int dw = dh2 * 16; dw < dh2 * 16 + 16; dw++)
          a = fdot2u(kp[(size_t)dw * NN], ph[dw], a);
        sPart[tid] = a;
      }
      __syncthreads();
      float* sPr = sX + 1536;  // spatial probs [256]
      if (tid < 256) {  // softmax stage 1 (full-block sync'd)
        float sc = (sPart[tid] + sPart[256 + tid]) * 0.125f;
        sPr[tid] = sc;
        int w = tid >> 6, lane = tid & 63;
        float mx = sc;
        #pragma unroll
        for (int s = 32; s >= 1; s >>= 1) mx = fmaxf(mx, __shfl_xor(mx, s));
        if (lane == 0) sAux[w] = mx;
      }
      __syncthreads();
      if (tid < 256) {  // softmax stage 2
        int w = tid >> 6, lane = tid & 63;
        float mx = fmaxf(fmaxf(sAux[0], sAux[1]), fmaxf(sAux[2], sAux[3]));
        float e = __expf(sPr[tid] - mx);
        sPr[tid] = e;
        float s2 = e;
        #pragma unroll
        for (int s = 32; s >= 1; s >>= 1) s2 += __shfl_xor(s2, s);
        if (lane == 0) sAux[4 + w] = s2;
      }
      __syncthreads();
      {
        int g = tid >> 6, d = tid & 63;
        float inv = 1.f / (sAux[4] + sAux[5] + sAux[6] + sAux[7]);
        const ushort_t* vp = P.VsH + ((size_t)idx8 * NN + g * 32) * DH + d;
        float acc = 0.f;
        #pragma unroll 4
        for (int n = 0; n < 32; n++) acc += sPr[g * 32 + n] * h2f(vp[(size_t)n * DH]);
        sB[tid] = acc * inv;
      }
      __syncthreads();
      if (tid < 64) {   // aSP head-slice -> sX[64..128)
        float o = 0.f;
        #pragma unroll
        for (int i = 0; i < 8; i++) o += sB[i * 64 + tid];
        sX[64 + tid] = o;
      }
      __syncthreads();
      if (tid < 64)     // pack aSA|aSP pairs -> ph[32..96)
        ph[32 + tid] = f2pk(sX[2 * tid], sX[2 * tid + 1]);
      __syncthreads();

      // ---- u1/ctx k-chunk-h partials: row-slice dot2 gemv + disjoint store -
      {
        float* ctp = ((t & 1) ? P.ctp1 : P.ctp0) + ((size_t)b * NH + h) * DD;
        float* u1p = P.u1p + ((size_t)b * NH + h) * DD;
        const uint2* wpa = (const uint2*)(P.w8 + 4ull * DD * DD) + tid;
        const uint2* wpb = (const uint2*)(P.w8 + 5ull * DD * DD) + tid;
        float acc1 = (h == 0) ? P.sa_bo[tid] + xrow[tid] : 0.f;
        float acc2 = (h == 0) ? P.s_bo[tid] : 0.f;
        #pragma unroll 8
        for (int j = 0; j < 16; j++) {
          int k4 = h * 16 + j;
          uint2 wv = wpa[(size_t)k4 * DD];
          uint2 x1 = *(const uint2*)&ph[32 + 2 * j];
          acc1 = fdot2u(wv.x, x1.x, acc1);
          acc1 = fdot2u(wv.y, x1.y, acc1);
          uint2 wv2 = wpb[(size_t)k4 * DD];
          uint2 x2 = *(const uint2*)&ph[64 + 2 * j];
          acc2 = fdot2u(wv2.x, x2.x, acc2);
          acc2 = fdot2u(wv2.y, x2.y, acc2);
        }
        stg_a(&u1p[tid], acc1);
        stg_a(&ctp[tid], acc2);
      }
    }
    gbar(fl, tid, h, rnd);

    // ==== Phase B: sum u1p -> LN1 -> y1s ; qc ; cross-attn ; u2 partial =====
    {
      float u = 0.f;
      {
        const float* pp = P.u1p + (size_t)b * NH * DD + tid;
        #pragma unroll
        for (int i = 0; i < 8; i++) u += ldg_a(pp + i * DD);
      }
      {
        int w = tid >> 6, lane = tid & 63;
        float s = u, q2 = u * u;
        #pragma unroll
        for (int m = 32; m >= 1; m >>= 1) { s += __shfl_xor(s, m); q2 += __shfl_xor(q2, m); }
        if (lane == 0) { sAux[w] = s; sAux[8 + w] = q2; }
      }
      __syncthreads();
      {
        float ss = 0.f, qq = 0.f;
        #pragma unroll
        for (int i = 0; i < 8; i++) { ss += sAux[i]; qq += sAux[8 + i]; }
        float mean = ss * (1.f / 512.f);
        float inv = rsqrtf(qq * (1.f / 512.f) - mean * mean + 1e-5f);
        y1s[tid] = (u - mean) * inv * P.ln1w[tid] + P.ln1b[tid];
      }
      __syncthreads();
      if (tid < 256) ph[128 + tid] = f2pk(y1s[2 * tid], y1s[2 * tid + 1]);
      __syncthreads();
      {  // qc: 8 k-chunks of 64, dot2
        int c = tid & 63, w = tid >> 6, col = h * DH + c;
        const uint2* wp = (const uint2*)(P.w8 + 6ull * DD * DD) + col;
        float acc = 0.f;
        #pragma unroll 8
        for (int kq = w * 16; kq < w * 16 + 16; kq++) {
          uint2 wv = wp[(size_t)kq * DD];
          uint2 xv = *(const uint2*)&ph[128 + 2 * kq];
          acc = fdot2u(wv.x, xv.x, acc);
          acc = fdot2u(wv.y, xv.y, acc);
        }
        sPart[tid] = acc;
      }
      __syncthreads();
      float* sQc = sX + 512;
      if (tid < 64) {
        float acc = 0.f;
        #pragma unroll
        for (int i = 0; i < 8; i++) acc += sPart[i * 64 + tid];
        sQc[tid] = acc + P.ca_bq[h * DH + tid];
      }
      __syncthreads();
      if (tid < 32) ph[tid] = f2pk(sQc[2 * tid], sQc[2 * tid + 1]);
      __syncthreads();
      // cross-attn scores (d-pair dot2)
      {
        int n = tid & 255, dh2 = tid >> 8;
        const unsigned* kp = (const unsigned*)P.KcT +
                             (((size_t)b * DD + h * DH) >> 1) * NN + n;
        float a = 0.f;
        #pragma unroll 8
        for (int dw = dh2 * 16; dw < dh2 * 16 + 16; dw++)
          a = fdot2u(kp[(size_t)dw * NN], ph[dw], a);
        sPart[tid] = a;
      }
      __syncthreads();
      float* sPr = sX + 1536;
      if (tid < 256) {  // softmax stage 1
        float sc = (sPart[tid] + sPart[256 + tid]) * 0.125f;
        sPr[tid] = sc;
        int w = tid >> 6, lane = tid & 63;
        float mx = sc;
        #pragma unroll
        for (int s = 32; s >= 1; s >>= 1) mx = fmaxf(mx, __shfl_xor(mx, s));
        if (lane == 0) sAux[w] = mx;
      }
      __syncthreads();
      if (tid < 256) {  // softmax stage 2
        int w = tid >> 6, lane = tid & 63;
        float mx = fmaxf(fmaxf(sAux[0], sAux[1]), fmaxf(sAux[2], sAux[3]));
        float e = __expf(sPr[tid] - mx);
        sPr[tid] = e;
        float s2 = e;
        #pragma unroll
        for (int s = 32; s >= 1; s >>= 1) s2 += __shfl_xor(s2, s);
        if (lane == 0) sAux[4 + w] = s2;
      }
      __syncthreads();
      float* sB = sX + 1024;
      {
        int g = tid >> 6, d = tid & 63;
        float inv = 1.f / (sAux[4] + sAux[5] + sAux[6] + sAux[7]);
        const ushort_t* vp = P.VcH + ((size_t)idx8 * NN + g * 32) * DH + d;
        float acc = 0.f;
        #pragma unroll 4
        for (int n = 0; n < 32; n++) acc += sPr[g * 32 + n] * h2f(vp[(size_t)n * DH]);
        sB[tid] = acc * inv;
      }
      __syncthreads();
      if (tid < 64) {   // aCA head-slice -> sX[0..64)
        float o = 0.f;
        #pragma unroll
        for (int i = 0; i < 8; i++) o += sB[i * 64 + tid];
        sX[tid] = o;
      }
      __syncthreads();
      if (tid < 32) ph[32 + tid] = f2pk(sX[2 * tid], sX[2 * tid + 1]);
      __syncthreads();
      {  // u2 k-chunk-h partial -> disjoint store (h0 adds bias + y1 resid)
        const uint2* wp = (const uint2*)(P.w8 + 7ull * DD * DD) + tid;
        float acc = (h == 0) ? P.ca_bo[tid] + y1s[tid] : 0.f;
        #pragma unroll 8
        for (int j = 0; j < 16; j++) {
          int k4 = h * 16 + j;
          uint2 wv = wp[(size_t)k4 * DD];
          uint2 xv = *(const uint2*)&ph[32 + 2 * j];
          acc = fdot2u(wv.x, xv.x, acc);
          acc = fdot2u(wv.y, xv.y, acc);
        }
        stg_a(&P.u2p[((size_t)b * NH + h) * DD + tid], acc);
      }
    }
    gbar(fl, tid, h, rnd);

    // ==== Phase C: sum u2p -> LN2 -> zs ; FFN1 slice ; fused FFN2 partial ===
    {
      float v = 0.f;
      {
        const float* pp = P.u2p + (size_t)b * NH * DD + tid;
        #pragma unroll
        for (int i = 0; i < 8; i++) v += ldg_a(pp + i * DD);
      }
      {
        int w = tid >> 6, lane = tid & 63;
        float s = v, q2 = v * v;
        #pragma unroll
        for (int m = 32; m >= 1; m >>= 1) { s += __shfl_xor(s, m); q2 += __shfl_xor(q2, m); }
        if (lane == 0) { sAux[w] = s; sAux[8 + w] = q2; }
      }
      __syncthreads();
      {
        float ss = 0.f, qq = 0.f;
        #pragma unroll
        for (int i = 0; i < 8; i++) { ss += sAux[i]; qq += sAux[8 + i]; }
        float mean = ss * (1.f / 512.f);
        float inv = rsqrtf(qq * (1.f / 512.f) - mean * mean + 1e-5f);
        zs[tid] = (v - mean) * inv * P.ln2w[tid] + P.ln2b[tid];
      }
      __syncthreads();
      if (tid < 256) ph[128 + tid] = f2pk(zs[2 * tid], zs[2 * tid + 1]);
      __syncthreads();
      {  // FFN1: cols h*256..h*256+255, k split in 2 halves, dot2
        int c = tid & 255, half = tid >> 8, col = h * 256 + c;
        const uint2* wp = (const uint2*)P.w1b + col;
        float acc = 0.f;
        #pragma unroll 8
        for (int kq = half * 64; kq < half * 64 + 64; kq++) {
          uint2 wv = wp[(size_t)kq * DF];
          uint2 xv = *(const uint2*)&ph[128 + 2 * kq];
          acc = fdot2u(wv.x, xv.x, acc);
          acc = fdot2u(wv.y, xv.y, acc);
        }
        sPart[tid] = acc;
      }
      __syncthreads();
      float* hh = sX;  // relu hidden slice [256]
      if (tid < 256)
        hh[tid] = fmaxf(sPart[tid] + sPart[256 + tid] + P.b1[h * 256 + tid], 0.f);
      __syncthreads();
      if (tid < 128) ph[384 + tid] = f2pk(hh[2 * tid], hh[2 * tid + 1]);
      __syncthreads();
      {  // fused FFN2: u3 partial over k-chunk h (W2 rows h*256..+256), dot2
        const uint2* wp = (const uint2*)P.w2b + tid;
        float acc = (h == 0) ? zs[tid] + P.b2[tid] : 0.f;
        #pragma unroll 8
        for (int j = 0; j < 64; j++) {
          int k4 = h * 64 + j;
          uint2 wv = wp[(size_t)k4 * DD];
          uint2 xv = *(const uint2*)&ph[384 + 2 * j];
          acc = fdot2u(wv.x, xv.x, acc);
          acc = fdot2u(wv.y, xv.y, acc);
        }
        stg_a(&P.u3p[((size_t)b * NH + h) * DD + tid], acc);
      }
    }
    gbar(fl, tid, h, rnd);

    // ==== Phase E: sum u3p -> LN3 ; +ctx(sum) ; xrow=nxt+pe ; h0: out =======
    {
      float u = 0.f, ctxv = 0.f;
      {
        const float* pp = P.u3p + (size_t)b * NH * DD + tid;
        const float* cp = ((t & 1) ? P.ctp1 : P.ctp0) + (size_t)b * NH * DD + tid;
        #pragma unroll
        for (int i = 0; i < 8; i++) { u += ldg_a(pp + i * DD); ctxv += ldg_a(cp + i * DD); }
      }
      {
        int w = tid >> 6, lane = tid & 63;
        float s = u, q2 = u * u;
        #pragma unroll
        for (int m = 32; m >= 1; m >>= 1) { s += __shfl_xor(s, m); q2 += __shfl_xor(q2, m); }
        if (lane == 0) { sAux[w] = s; sAux[8 + w] = q2; }
      }
      __syncthreads();
      float ss = 0.f, qq = 0.f;
      #pragma unroll
      for (int i = 0; i < 8; i++) { ss += sAux[i]; qq += sAux[8 + i]; }
      float mean = ss * (1.f / 512.f);
      float inv = rsqrtf(qq * (1.f / 512.f) - mean * mean + 1e-5f);
      float nxt = (u - mean) * inv * P.ln3w[tid] + P.ln3b[tid] + ctxv;
      float p = (t < TT - 1) ? P.pe[(size_t)(t + 1) * DD + tid] : 0.f;
      if (h == 0) sX[tid] = nxt;
      __syncthreads();
      xrow[tid] = nxt + p;
      if (h == 0) {   // block-uniform branch: inner barrier legal
        {
          int c = tid >> 8, l = tid & 255;
          float a = sX[l] * P.Wout[(size_t)c * DD + l] +
                    sX[l + 256] * P.Wout[(size_t)c * DD + l + 256];
          #pragma unroll
          for (int m = 32; m >= 1; m >>= 1) a += __shfl_xor(a, m);
          if ((tid & 63) == 0) sAux[16 + (tid >> 6)] = a;
        }
        __syncthreads();
        if (tid == 0)
          P.out[((size_t)b * TT + t) * 2 + 0] =
              sAux[16] + sAux[17] + sAux[18] + sAux[19] + P.bout[0];
        if (tid == 256)
          P.out[((size_t)b * TT + t) * 2 + 1] =
              sAux[20] + sAux[21] + sAux[22] + sAux[23] + P.bout[1];
      }
      __syncthreads();
      if (tid < 256) xh[tid] = f2pk(xrow[2 * tid], xrow[2 * tid + 1]);
      __syncthreads();  // xrow/xh stable before next Phase A
    }
    // no barrier: A(t+1) writes only block-private state or the opposite
    // ctx parity buffer; u1p overwrite is >=2 barriers past its readers.
  }
}

// ---- precompute kernels -----------------------------------------------------
__global__ __launch_bounds__(256) void gemm_kv(
    const float* __restrict__ A,
    const float* __restrict__ W0, const float* __restrict__ W1_,
    const float* __restrict__ W2_, const float* __restrict__ W3_,
    const float* __restrict__ b0, const float* __restrict__ b1_,
    const float* __restrict__ b2_, const float* __restrict__ b3_,
    float* __restrict__ O0, float* __restrict__ O1,
    float* __restrict__ O2, float* __restrict__ O3) {
  __shared__ __align__(16) float As[8][128];
  __shared__ __align__(16) float Bs[8][128];
  int tid = threadIdx.x;
  int bx = blockIdx.x, by = blockIdx.y;
  int mm = bx >> 2;
  int col0 = (bx & 3) * 128;
  const float* W = mm == 0 ? W0 : mm == 1 ? W1_ : mm == 2 ? W2_ : W3_;
  const float* bias = mm == 0 ? b0 : mm == 1 ? b1_ : mm == 2 ? b2_ : b3_;
  float* O = mm == 0 ? O0 : mm == 1 ? O1 : mm == 2 ? O2 : O3;
  int tx = tid & 15, ty = tid >> 4;
  int m0 = by * 128;
  int lr = tid >> 1, lk = (tid & 1) * 4;
  const float* Ap = A + (size_t)(m0 + lr) * DD + lk;
  const float* Wp = W + (size_t)(col0 + lr) * DD + lk;
  float c[8][8] = {};
  for (int k0 = 0; k0 < DD; k0 += 8) {
    float4 av = *(const float4*)(Ap + k0);
    float4 wv = *(const float4*)(Wp + k0);
    __syncthreads();
    As[lk + 0][lr] = av.x; As[lk + 1][lr] = av.y; As[lk + 2][lr] = av.z; As[lk + 3][lr] = av.w;
    Bs[lk + 0][lr] = wv.x; Bs[lk + 1][lr] = wv.y; Bs[lk + 2][lr] = wv.z; Bs[lk + 3][lr] = wv.w;
    __syncthreads();
    #pragma unroll
    for (int k = 0; k < 8; k++) {
      float a[8], bb[8];
      *(float4*)&a[0] = *(const float4*)&As[k][ty * 8];
      *(float4*)&a[4] = *(const float4*)&As[k][ty * 8 + 4];
      *(float4*)&bb[0] = *(const float4*)&Bs[k][tx * 8];
      *(float4*)&bb[4] = *(const float4*)&Bs[k][tx * 8 + 4];
      #pragma unroll
      for (int i = 0; i < 8; i++)
        #pragma unroll
        for (int j = 0; j < 8; j++) c[i][j] += a[i] * bb[j];
    }
  }
  const float* bp = bias + col0 + tx * 8;
  for (int i = 0; i < 8; i++) {
    int row = m0 + ty * 8 + i;
    float* op = O + (size_t)row * DD + col0 + tx * 8;
    #pragma unroll
    for (int jq = 0; jq < 8; jq += 4) {
      float4 v;
      v.x = c[i][jq + 0] + bp[jq + 0];
      v.y = c[i][jq + 1] + bp[jq + 1];
      v.z = c[i][jq + 2] + bp[jq + 2];
      v.w = c[i][jq + 3] + bp[jq + 3];
      *(float4*)(op + jq) = v;
    }
  }
}

// K^T packed d-pair layout: uint word w = (d>>1)*NN + n holds f16 elements
// (d, n) in low half (d even) and (d+1, n) in high half.
__global__ __launch_bounds__(256) void pack_kT(const float* __restrict__ Ks32,
                                               const float* __restrict__ Kc32,
                                               ushort_t* __restrict__ KsT,
                                               ushort_t* __restrict__ KcT) {
  int z = blockIdx.z;
  int b = z >> 1;
  const float* in = ((z & 1) ? Kc32 : Ks32) + (size_t)b * NN * DD;
  ushort_t* out = ((z & 1) ? KcT : KsT) + (size_t)b * NN * DD;
  int r0 = blockIdx.x * 32, c0 = blockIdx.y * 32;
  __shared__ float tile[32][33];
  int tid = threadIdx.x;
  int i = tid >> 3, j4 = (tid & 7) * 4;
  float4 v = *(const float4*)(in + (size_t)(r0 + i) * DD + c0 + j4);
  tile[i][j4] = v.x; tile[i][j4 + 1] = v.y; tile[i][j4 + 2] = v.z; tile[i][j4 + 3] = v.w;
  __syncthreads();
  int d = c0 + i;
  ushort_t* op = out + (size_t)(d >> 1) * (2 * NN) + 2 * (r0 + j4) + (d & 1);
  op[0] = f2h(tile[j4][i]);     op[2] = f2h(tile[j4 + 1][i]);
  op[4] = f2h(tile[j4 + 2][i]); op[6] = f2h(tile[j4 + 3][i]);
}

__global__ __launch_bounds__(256) void pack_vh(const float* __restrict__ Vs32,
                                               const float* __restrict__ Vc32,
                                               ushort_t* __restrict__ VsH,
                                               ushort_t* __restrict__ VcH) {
  const float* src = blockIdx.y ? Vc32 : Vs32;
  ushort_t* dst = blockIdx.y ? VcH : VsH;
  size_t idx = (size_t)blockIdx.x * 1024 + threadIdx.x * 4;
  float4 v = *(const float4*)(src + idx);
  int d512 = (int)(idx & 511);
  int n = (int)((idx >> 9) & 255);
  int b = (int)(idx >> 17);
  int h = d512 >> 6, d = d512 & 63;
  ushort_t* op = dst + (((size_t)(b * 8 + h) * NN + n) * DH + d);
  op[0] = f2h(v.x); op[1] = f2h(v.y); op[2] = f2h(v.z); op[3] = f2h(v.w);
}

struct PWItem { const float* in; ushort_t* out; int C; int K; };
struct PWArgs { PWItem m[10]; };
__global__ __launch_bounds__(256) void pack_w(PWArgs a) {
  PWItem it = a.m[blockIdx.y];
  int total = it.C * (it.K >> 2);
  int e = blockIdx.x * 256 + threadIdx.x;
  if (e >= total) return;
  int kd = it.K >> 2;
  int k4 = e % kd, col = e / kd;
  float4 v = *(const float4*)(it.in + (size_t)col * it.K + k4 * 4);
  unsigned lo = f2pk(v.x, v.y), hi = f2pk(v.z, v.w);
  ushort4 o;
  o.x = (ushort_t)(lo & 0xffffu); o.y = (ushort_t)(lo >> 16);
  o.z = (ushort_t)(hi & 0xffffu); o.w = (ushort_t)(hi >> 16);
  *((ushort4*)it.out + (size_t)k4 * it.C + col) = o;
}

__global__ __launch_bounds__(256) void init_x(const float* __restrict__ hv0,
                                              const float* __restrict__ pe,
                                              float* __restrict__ ws,
                                              unsigned* __restrict__ flags) {
  int i = blockIdx.x * 256 + threadIdx.x;
  ws[OFF_X + i] = hv0[i] + pe[i & (DD - 1)];
  if (i < 2048) flags[i] = 0u;
}

// ---------------------------------------------------------------------------
extern "C" void kernel_launch(void* const* d_in, const int* in_sizes, int n_in,
                              void* d_out, int out_size, void* d_ws, size_t ws_size,
                              hipStream_t stream) {
  const float* H_v_all = (const float*)d_in[0];
  const float* H_v0    = (const float*)d_in[1];
  const float* pe      = (const float*)d_in[2];
  const float* s_Wq = (const float*)d_in[3];
  const float* s_Wk = (const float*)d_in[4];
  const float* s_Wv = (const float*)d_in[5];
  const float* s_Wo = (const float*)d_in[6];
  const float* s_bq = (const float*)d_in[7];
  const float* s_bk = (const float*)d_in[8];
  const float* s_bv = (const float*)d_in[9];
  const float* s_bo = (const float*)d_in[10];
  const float* sa_Wq = (const float*)d_in[11];
  const float* sa_Wk = (const float*)d_in[12];
  const float* sa_Wv = (const float*)d_in[13];
  const float* sa_Wo = (const float*)d_in[14];
  const float* sa_bq = (const float*)d_in[15];
  const float* sa_bk = (const float*)d_in[16];
  const float* sa_bv = (const float*)d_in[17];
  const float* sa_bo = (const float*)d_in[18];
  const float* ca_Wq = (const float*)d_in[19];
  const float* ca_Wk = (const float*)d_in[20];
  const float* ca_Wv = (const float*)d_in[21];
  const float* ca_Wo = (const float*)d_in[22];
  const float* ca_bq = (const float*)d_in[23];
  const float* ca_bk = (const float*)d_in[24];
  const float* ca_bv = (const float*)d_in[25];
  const float* ca_bo = (const float*)d_in[26];
  const float* ln1w = (const float*)d_in[27];
  const float* ln1b = (const float*)d_in[28];
  const float* ln2w = (const float*)d_in[29];
  const float* ln2b = (const float*)d_in[30];
  const float* ln3w = (const float*)d_in[31];
  const float* ln3b = (const float*)d_in[32];
  const float* W1   = (const float*)d_in[33];
  const float* b1   = (const float*)d_in[34];
  const float* W2   = (const float*)d_in[35];
  const float* b2   = (const float*)d_in[36];
  const float* Wout = (const float*)d_in[37];
  const float* bout = (const float*)d_in[38];

  float* ws = (float*)d_ws;
  float* Ks32 = ws + OFF_KS32;
  float* Vs32 = ws + OFF_VS32;
  float* Kc32 = ws + OFF_KC32;
  float* Vc32 = ws + OFF_VC32;
  ushort_t* ub = (ushort_t*)(ws + OFF_BF);
  unsigned* flags = (unsigned*)(ws + OFF_FLG);

  hipLaunchKernelGGL(gemm_kv, dim3(16, 64), dim3(256), 0, stream,
                     H_v_all, s_Wk, s_Wv, ca_Wk, ca_Wv,
                     s_bk, s_bv, ca_bk, ca_bv, Ks32, Vs32, Kc32, Vc32);

  hipLaunchKernelGGL(pack_kT, dim3(8, 16, 64), dim3(256), 0, stream,
                     Ks32, Kc32, ub + UOFF_KST, ub + UOFF_KCT);
  hipLaunchKernelGGL(pack_vh, dim3((unsigned)(SZ_KV / 1024), 2), dim3(256), 0,
                     stream, Vs32, Vc32, ub + UOFF_VSH, ub + UOFF_VCH);

  PWArgs pw;
  pw.m[0] = {sa_Wq, ub + UOFF_W8 + 0ull * DD * DD, DD, DD};
  pw.m[1] = {sa_Wk, ub + UOFF_W8 + 1ull * DD * DD, DD, DD};
  pw.m[2] = {sa_Wv, ub + UOFF_W8 + 2ull * DD * DD, DD, DD};
  pw.m[3] = {s_Wq,  ub + UOFF_W8 + 3ull * DD * DD, DD, DD};
  pw.m[4] = {sa_Wo, ub + UOFF_W8 + 4ull * DD * DD, DD, DD};
  pw.m[5] = {s_Wo,  ub + UOFF_W8 + 5ull * DD * DD, DD, DD};
  pw.m[6] = {ca_Wq, ub + UOFF_W8 + 6ull * DD * DD, DD, DD};
  pw.m[7] = {ca_Wo, ub + UOFF_W8 + 7ull * DD * DD, DD, DD};
  pw.m[8] = {W1, ub + UOFF_W1, DF, DD};
  pw.m[9] = {W2, ub + UOFF_W2, DD, DF};
  hipLaunchKernelGGL(pack_w, dim3(1024, 10), dim3(256), 0, stream, pw);

  hipLaunchKernelGGL(init_x, dim3(64), dim3(256), 0, stream,
                     H_v0, pe, ws, flags);

  Params P;
  P.pe = pe;
  P.sa_bq = sa_bq; P.sa_bk = sa_bk; P.sa_bv = sa_bv; P.s_bq = s_bq;
  P.sa_bo = sa_bo; P.s_bo = s_bo; P.ca_bq = ca_bq; P.ca_bo = ca_bo;
  P.ln1w = ln1w; P.ln1b = ln1b; P.ln2w = ln2w; P.ln2b = ln2b;
  P.ln3w = ln3w; P.ln3b = ln3b;
  P.b1 = b1; P.b2 = b2; P.Wout = Wout; P.bout = bout;
  P.w8 = ub + UOFF_W8; P.w1b = ub + UOFF_W1; P.w2b = ub + UOFF_W2;
  P.KsT = ub + UOFF_KST; P.KcT = ub + UOFF_KCT;
  P.VsH = ub + UOFF_VSH; P.VcH = ub + UOFF_VCH;
  P.KsaB = ub + UOFF_KSA; P.VsaB = ub + UOFF_VSA;
  P.xcur = ws + OFF_X;
  P.u1p = ws + OFF_U1P; P.u2p = ws + OFF_U2P; P.u3p = ws + OFF_U3P;
  P.ctp0 = ws + OFF_CTP0; P.ctp1 = ws + OFF_CTP1;
  P.out = (float*)d_out;
  P.flags = flags;

  void* kargs[] = { (void*)&P };
  hipLaunchCooperativeKernel((void*)decode_persistent, dim3(NBLK), dim3(NTHR),
                             kargs, 0, stream);
}

// Round 5
// 2208.302 us; speedup vs baseline: 2.5295x; 1.2029x over previous
//
#include <hip/hip_runtime.h>

// ---------------------------------------------------------------------------
// VehicleTrajectoryDecoder: B=32, N=256, D=512, H=8 (dh=64), T=60, DFF=2048.
// R14: R13 (2291us) left ~33us/step of stall with VALU busy only 4.7us/step.
// FETCH_SIZE = 30MB/step == the full packed KV set: per-XCD KV slice (4MB) +
// weights don't fit the 4MB L2, so K/V stream from L3/HBM inside the
// dependency-gated score/PV stages every step. R14 stages each block's
// four KV slices (Ks/Kc d-pair words, Vs/Vc head-major; 32KB each, all
// contiguous) into 128KB of DYNAMIC LDS once at kernel start and reads them
// from LDS for all 60 steps. Static (19.5KB) + dynamic = 147.5KB < 160KB/CU
// (1 block/CU). hipFuncSetAttribute raises the dynamic-LDS cap (host-side,
// not a stream op -> graph-capture safe). Score reads are lane-consecutive
// (conflict-free); PV reads 2 lanes/bank (free). Everything else (4 fused
// phases, 3 symmetric 1-RTT barriers/step, head==XCD, slab exchange, f16
// dot2 math) unchanged from R13.
// ---------------------------------------------------------------------------

#define NB 32
#define NN 256
#define DD 512
#define NH 8
#define DH 64
#define TT 60
#define DF 2048
#define NBLK 256
#define NTHR 512

typedef unsigned short ushort_t;
typedef _Float16 half2v __attribute__((ext_vector_type(2)));

// ---- workspace layout ------------------------------------------------------
constexpr size_t SZ_KV  = (size_t)NB * NN * DD;   // 4194304
constexpr size_t SZ_ROW = (size_t)NB * DD;
constexpr size_t SZ_PAR = (size_t)NB * NH * DD;   // 131072 (partial slabs)
constexpr size_t SZ_SAB = (size_t)NB * NH * TT * DH;
constexpr size_t OFF_KS32 = 0;
constexpr size_t OFF_VS32 = SZ_KV;
constexpr size_t OFF_KC32 = 2 * SZ_KV;
constexpr size_t OFF_VC32 = 3 * SZ_KV;
constexpr size_t OFF_X    = 0;
constexpr size_t OFF_U1P  = OFF_X   + SZ_ROW;
constexpr size_t OFF_U2P  = OFF_U1P + SZ_PAR;
constexpr size_t OFF_U3P  = OFF_U2P + SZ_PAR;
constexpr size_t OFF_CTP0 = OFF_U3P + SZ_PAR;
constexpr size_t OFF_CTP1 = OFF_CTP0 + SZ_PAR;
constexpr size_t OFF_BF   = 4 * SZ_KV;
constexpr size_t UOFF_KST = 0;
constexpr size_t UOFF_KCT = SZ_KV;
constexpr size_t UOFF_VSH = 2 * SZ_KV;
constexpr size_t UOFF_VCH = 3 * SZ_KV;
constexpr size_t UOFF_KSA = 4 * SZ_KV;
constexpr size_t UOFF_VSA = UOFF_KSA + SZ_SAB;
constexpr size_t UOFF_W8  = UOFF_VSA + SZ_SAB;
constexpr size_t UOFF_W1  = UOFF_W8 + 8ull * DD * DD;
constexpr size_t UOFF_W2  = UOFF_W1 + (size_t)DD * DF;
constexpr size_t UEND     = UOFF_W2 + (size_t)DF * DD;
constexpr size_t OFF_FLG  = OFF_BF + (UEND + 1) / 2;

constexpr unsigned DYN_LDS = 131072;  // 4 x 32KB KV slices

// ---- helpers ----------------------------------------------------------------
__device__ __forceinline__ float ldg_a(const float* p) {
  return __hip_atomic_load(p, __ATOMIC_RELAXED, __HIP_MEMORY_SCOPE_AGENT);
}
__device__ __forceinline__ void stg_a(float* p, float v) {
  __hip_atomic_store(p, v, __ATOMIC_RELAXED, __HIP_MEMORY_SCOPE_AGENT);
}
__device__ __forceinline__ unsigned f2pk(float a, float b) {
  return __builtin_bit_cast(unsigned, __builtin_amdgcn_cvt_pkrtz(a, b));
}
__device__ __forceinline__ ushort_t f2h(float a) {
  return (ushort_t)(f2pk(a, 0.f) & 0xffffu);
}
__device__ __forceinline__ float h2f(ushort_t u) {
  return (float)__builtin_bit_cast(_Float16, u);
}
__device__ __forceinline__ float fdot2u(unsigned a, unsigned b, float c) {
  return __builtin_amdgcn_fdot2(__builtin_bit_cast(half2v, a),
                                __builtin_bit_cast(half2v, b), c, false);
}

// ---- params ----------------------------------------------------------------
struct Params {
  const float *pe;
  const float *sa_bq, *sa_bk, *sa_bv, *s_bq, *sa_bo, *s_bo, *ca_bq, *ca_bo;
  const float *ln1w, *ln1b, *ln2w, *ln2b, *ln3w, *ln3b;
  const float *b1, *b2, *Wout, *bout;
  const ushort_t *w8, *w1b, *w2b;
  const ushort_t *KsT, *KcT, *VsH, *VcH;
  ushort_t *KsaB, *VsaB;
  float *xcur, *u1p, *u2p, *u3p, *ctp0, *ctp1;
  float *out;
  unsigned *flags;
};

// ---- symmetric per-batch 8-block barrier (1 RTT) ---------------------------
__device__ __forceinline__ void gbar(unsigned* fl, int tid, int h,
                                     unsigned& rnd) {
  __builtin_amdgcn_s_waitcnt(0);
  __syncthreads();
  rnd++;
  if (tid < 64) {
    if (tid == h)
      __hip_atomic_store(&fl[h], rnd, __ATOMIC_RELAXED,
                         __HIP_MEMORY_SCOPE_AGENT);
    bool wait = true;
    while (wait) {
      unsigned v = rnd;
      if (tid < 8)
        v = __hip_atomic_load(&fl[tid], __ATOMIC_RELAXED,
                              __HIP_MEMORY_SCOPE_AGENT);
      wait = __any(v < rnd);
    }
  }
  __syncthreads();
}

// ---- persistent decode (256 blocks x 512 threads; 32 batches x 8 heads) ----
__global__ __launch_bounds__(512) void decode_persistent(Params P) {
  __shared__ __align__(16) float sX[2048];    // scratch
  __shared__ __align__(16) float sPart[512];
  __shared__ float sAux[64];
  __shared__ __align__(16) float xrow[512];   // persistent x (incl. pe)
  __shared__ __align__(16) float y1s[512];    // LN1 output row
  __shared__ __align__(16) float zs[512];     // LN2 output row
  __shared__ __align__(16) unsigned xh[256];  // xrow packed f16 pairs
  __shared__ __align__(16) unsigned ph[512];  // packed scratch (per-phase)
  extern __shared__ __align__(16) unsigned dynLds[];  // 128KB KV slices
  unsigned* Ks_l = dynLds;                    // [32 dw][256 n] words
  unsigned* Kc_l = dynLds + 8192;
  ushort_t* Vs_l = (ushort_t*)(dynLds + 16384);  // [256 n][64 d]
  ushort_t* Vc_l = Vs_l + 16384;

  int tid = threadIdx.x;
  int bid = blockIdx.x;
  int b = bid >> 3, h = bid & 7;              // XCD = bid mod 8 = h  (key!)
  int idx8 = bid;                             // (b,h) linear index
  unsigned* fl = P.flags + b * 64;
  unsigned rnd = 0;

  // ---- one-time KV staging: 4 contiguous 32KB slices -> LDS ----
  {
    const uint4* gks = (const uint4*)((const unsigned*)P.KsT +
                       (((size_t)b * DD + h * DH) >> 1) * NN);
    const uint4* gkc = (const uint4*)((const unsigned*)P.KcT +
                       (((size_t)b * DD + h * DH) >> 1) * NN);
    const uint4* gvs = (const uint4*)(P.VsH + (size_t)idx8 * NN * DH);
    const uint4* gvc = (const uint4*)(P.VcH + (size_t)idx8 * NN * DH);
    uint4* dks = (uint4*)Ks_l;
    uint4* dkc = (uint4*)Kc_l;
    uint4* dvs = (uint4*)Vs_l;
    uint4* dvc = (uint4*)Vc_l;
    #pragma unroll
    for (int i = 0; i < 4; i++) {
      int idx = i * NTHR + tid;               // 2048 uint4 per slice
      dks[idx] = gks[idx];
      dkc[idx] = gkc[idx];
      dvs[idx] = gvs[idx];
      dvc[idx] = gvc[idx];
    }
  }

  xrow[tid] = ldg_a(P.xcur + (size_t)b * DD + tid);
  __syncthreads();
  if (tid < 256) xh[tid] = f2pk(xrow[2 * tid], xrow[2 * tid + 1]);
  __syncthreads();

  for (int t = 0; t < TT; t++) {
    // ==== Phase A: proj q/k/v/qs + self-attn + spatial + u1/ctx partials ====
    {
      // proj: wave w: matrix m=w>>1, k-half=w&1; lane c -> col h*64+c
      {
        int w = tid >> 6, c = tid & 63, m = w >> 1, half = w & 1;
        int col = h * DH + c;
        const uint2* wp = (const uint2*)(P.w8 + (size_t)m * DD * DD) + col;
        float acc = 0.f;
        #pragma unroll 8
        for (int kq = half * 64; kq < half * 64 + 64; kq++) {
          uint2 wv = wp[(size_t)kq * DD];
          uint2 xv = *(const uint2*)&xh[kq * 2];
          acc = fdot2u(wv.x, xv.x, acc);
          acc = fdot2u(wv.y, xv.y, acc);
        }
        sPart[tid] = acc;
      }
      __syncthreads();
      if (tid < 256) {  // combine halves + bias; stash in sX[512..768)
        int m = tid >> 6, c = tid & 63, col = h * DH + c;
        const float* bias = (m == 0) ? P.sa_bq : (m == 1) ? P.sa_bk
                          : (m == 2) ? P.sa_bv : P.s_bq;
        float val = sPart[(2 * m) * 64 + c] + sPart[(2 * m + 1) * 64 + c]
                    + bias[col];
        sX[512 + tid] = val;
        if (m == 1) P.KsaB[((size_t)idx8 * TT + t) * DH + c] = f2h(val);
        if (m == 2) P.VsaB[((size_t)idx8 * TT + t) * DH + c] = f2h(val);
      }
      __syncthreads();

      // ---- self-attn over L keys (head-private f16 cache) ----
      int L = t + 1;
      float* sQ  = sX + 512;        // q_self [64]
      float* sQs = sX + 704;        // q_spatial [64]
      float* sPb = sX + 768;        // self probs [64]
      float* sB  = sX + 1024;       // partials [512]
      if (tid < 64) {
        float sc = -1e30f;
        if (tid < L) {
          const ushort_t* kp = P.KsaB + ((size_t)idx8 * TT + tid) * DH;
          float a = 0.f;
          #pragma unroll
          for (int i = 0; i < DH; i += 4) {
            ushort4 kv = *(const ushort4*)(kp + i);
            a += sQ[i] * h2f(kv.x) + sQ[i + 1] * h2f(kv.y) +
                 sQ[i + 2] * h2f(kv.z) + sQ[i + 3] * h2f(kv.w);
          }
          sc = a * 0.125f;
        }
        float mx = sc;
        #pragma unroll
        for (int s = 32; s >= 1; s >>= 1) mx = fmaxf(mx, __shfl_xor(mx, s));
        float e = (tid < L) ? __expf(sc - mx) : 0.f;
        float s2 = e;
        #pragma unroll
        for (int s = 32; s >= 1; s >>= 1) s2 += __shfl_xor(s2, s);
        sPb[tid] = e;
        if (tid == 0) sAux[12] = 1.f / s2;
      } else if (tid < 96) {   // pack q_spatial pairs -> ph[0..32)
        int i = tid - 64;
        ph[i] = f2pk(sQs[2 * i], sQs[2 * i + 1]);
      }
      __syncthreads();
      {  // PV: 8 key-groups x 64 d
        int g = tid >> 6, d = tid & 63;
        float a2 = 0.f;
        for (int j = g; j < L; j += 8)
          a2 += sPb[j] * h2f(P.VsaB[((size_t)idx8 * TT + j) * DH + d]);
        sB[tid] = a2;
      }
      __syncthreads();
      if (tid < 64) {   // aSA head-slice -> sX[0..64)
        float o = 0.f;
        #pragma unroll
        for (int i = 0; i < 8; i++) o += sB[i * 64 + tid];
        sX[tid] = o * sAux[12];
      }
      __syncthreads();

      // ---- spatial attn over 256 keys (LDS K, d-pair dot2; LDS V PV) ----
      {
        int n = tid & 255, dh2 = tid >> 8;
        const unsigned* kp = Ks_l + n;
        float a = 0.f;
        #pragma unroll 8
        for (int dw = dh2 * 16; dw < dh2 * 16 + 16; dw++)
          a = fdot2u(kp[dw * NN], ph[dw], a);
        sPart[tid] = a;
      }
      __syncthreads();
      float* sPr = sX + 1536;  // spatial probs [256]
      if (tid < 256) {  // softmax stage 1 (full-block sync'd)
        float sc = (sPart[tid] + sPart[256 + tid]) * 0.125f;
        sPr[tid] = sc;
        int w = tid >> 6, lane = tid & 63;
        float mx = sc;
        #pragma unroll
        for (int s = 32; s >= 1; s >>= 1) mx = fmaxf(mx, __shfl_xor(mx, s));
        if (lane == 0) sAux[w] = mx;
      }
      __syncthreads();
      if (tid < 256) {  // softmax stage 2
        int w = tid >> 6, lane = tid & 63;
        float mx = fmaxf(fmaxf(sAux[0], sAux[1]), fmaxf(sAux[2], sAux[3]));
        float e = __expf(sPr[tid] - mx);
        sPr[tid] = e;
        float s2 = e;
        #pragma unroll
        for (int s = 32; s >= 1; s >>= 1) s2 += __shfl_xor(s2, s);
        if (lane == 0) sAux[4 + w] = s2;
      }
      __syncthreads();
      {
        int g = tid >> 6, d = tid & 63;
        float inv = 1.f / (sAux[4] + sAux[5] + sAux[6] + sAux[7]);
        const ushort_t* vp = Vs_l + (g * 32) * DH + d;
        float acc = 0.f;
        #pragma unroll 4
        for (int n = 0; n < 32; n++) acc += sPr[g * 32 + n] * h2f(vp[n * DH]);
        sB[tid] = acc * inv;
      }
      __syncthreads();
      if (tid < 64) {   // aSP head-slice -> sX[64..128)
        float o = 0.f;
        #pragma unroll
        for (int i = 0; i < 8; i++) o += sB[i * 64 + tid];
        sX[64 + tid] = o;
      }
      __syncthreads();
      if (tid < 64)     // pack aSA|aSP pairs -> ph[32..96)
        ph[32 + tid] = f2pk(sX[2 * tid], sX[2 * tid + 1]);
      __syncthreads();

      // ---- u1/ctx k-chunk-h partials: row-slice dot2 gemv + disjoint store -
      {
        float* ctp = ((t & 1) ? P.ctp1 : P.ctp0) + ((size_t)b * NH + h) * DD;
        float* u1p = P.u1p + ((size_t)b * NH + h) * DD;
        const uint2* wpa = (const uint2*)(P.w8 + 4ull * DD * DD) + tid;
        const uint2* wpb = (const uint2*)(P.w8 + 5ull * DD * DD) + tid;
        float acc1 = (h == 0) ? P.sa_bo[tid] + xrow[tid] : 0.f;
        float acc2 = (h == 0) ? P.s_bo[tid] : 0.f;
        #pragma unroll 8
        for (int j = 0; j < 16; j++) {
          int k4 = h * 16 + j;
          uint2 wv = wpa[(size_t)k4 * DD];
          uint2 x1 = *(const uint2*)&ph[32 + 2 * j];
          acc1 = fdot2u(wv.x, x1.x, acc1);
          acc1 = fdot2u(wv.y, x1.y, acc1);
          uint2 wv2 = wpb[(size_t)k4 * DD];
          uint2 x2 = *(const uint2*)&ph[64 + 2 * j];
          acc2 = fdot2u(wv2.x, x2.x, acc2);
          acc2 = fdot2u(wv2.y, x2.y, acc2);
        }
        stg_a(&u1p[tid], acc1);
        stg_a(&ctp[tid], acc2);
      }
    }
    gbar(fl, tid, h, rnd);

    // ==== Phase B: sum u1p -> LN1 -> y1s ; qc ; cross-attn ; u2 partial =====
    {
      float u = 0.f;
      {
        const float* pp = P.u1p + (size_t)b * NH * DD + tid;
        #pragma unroll
        for (int i = 0; i < 8; i++) u += ldg_a(pp + i * DD);
      }
      {
        int w = tid >> 6, lane = tid & 63;
        float s = u, q2 = u * u;
        #pragma unroll
        for (int m = 32; m >= 1; m >>= 1) { s += __shfl_xor(s, m); q2 += __shfl_xor(q2, m); }
        if (lane == 0) { sAux[w] = s; sAux[8 + w] = q2; }
      }
      __syncthreads();
      {
        float ss = 0.f, qq = 0.f;
        #pragma unroll
        for (int i = 0; i < 8; i++) { ss += sAux[i]; qq += sAux[8 + i]; }
        float mean = ss * (1.f / 512.f);
        float inv = rsqrtf(qq * (1.f / 512.f) - mean * mean + 1e-5f);
        y1s[tid] = (u - mean) * inv * P.ln1w[tid] + P.ln1b[tid];
      }
      __syncthreads();
      if (tid < 256) ph[128 + tid] = f2pk(y1s[2 * tid], y1s[2 * tid + 1]);
      __syncthreads();
      {  // qc: 8 k-chunks of 64, dot2
        int c = tid & 63, w = tid >> 6, col = h * DH + c;
        const uint2* wp = (const uint2*)(P.w8 + 6ull * DD * DD) + col;
        float acc = 0.f;
        #pragma unroll 8
        for (int kq = w * 16; kq < w * 16 + 16; kq++) {
          uint2 wv = wp[(size_t)kq * DD];
          uint2 xv = *(const uint2*)&ph[128 + 2 * kq];
          acc = fdot2u(wv.x, xv.x, acc);
          acc = fdot2u(wv.y, xv.y, acc);
        }
        sPart[tid] = acc;
      }
      __syncthreads();
      float* sQc = sX + 512;
      if (tid < 64) {
        float acc = 0.f;
        #pragma unroll
        for (int i = 0; i < 8; i++) acc += sPart[i * 64 + tid];
        sQc[tid] = acc + P.ca_bq[h * DH + tid];
      }
      __syncthreads();
      if (tid < 32) ph[tid] = f2pk(sQc[2 * tid], sQc[2 * tid + 1]);
      __syncthreads();
      // cross-attn scores (LDS K, d-pair dot2)
      {
        int n = tid & 255, dh2 = tid >> 8;
        const unsigned* kp = Kc_l + n;
        float a = 0.f;
        #pragma unroll 8
        for (int dw = dh2 * 16; dw < dh2 * 16 + 16; dw++)
          a = fdot2u(kp[dw * NN], ph[dw], a);
        sPart[tid] = a;
      }
      __syncthreads();
      float* sPr = sX + 1536;
      if (tid < 256) {  // softmax stage 1
        float sc = (sPart[tid] + sPart[256 + tid]) * 0.125f;
        sPr[tid] = sc;
        int w = tid >> 6, lane = tid & 63;
        float mx = sc;
        #pragma unroll
        for (int s = 32; s >= 1; s >>= 1) mx = fmaxf(mx, __shfl_xor(mx, s));
        if (lane == 0) sAux[w] = mx;
      }
      __syncthreads();
      if (tid < 256) {  // softmax stage 2
        int w = tid >> 6, lane = tid & 63;
        float mx = fmaxf(fmaxf(sAux[0], sAux[1]), fmaxf(sAux[2], sAux[3]));
        float e = __expf(sPr[tid] - mx);
        sPr[tid] = e;
        float s2 = e;
        #pragma unroll
        for (int s = 32; s >= 1; s >>= 1) s2 += __shfl_xor(s2, s);
        if (lane == 0) sAux[4 + w] = s2;
      }
      __syncthreads();
      float* sB = sX + 1024;
      {
        int g = tid >> 6, d = tid & 63;
        float inv = 1.f / (sAux[4] + sAux[5] + sAux[6] + sAux[7]);
        const ushort_t* vp = Vc_l + (g * 32) * DH + d;
        float acc = 0.f;
        #pragma unroll 4
        for (int n = 0; n < 32; n++) acc += sPr[g * 32 + n] * h2f(vp[n * DH]);
        sB[tid] = acc * inv;
      }
      __syncthreads();
      if (tid < 64) {   // aCA head-slice -> sX[0..64)
        float o = 0.f;
        #pragma unroll
        for (int i = 0; i < 8; i++) o += sB[i * 64 + tid];
        sX[tid] = o;
      }
      __syncthreads();
      if (tid < 32) ph[32 + tid] = f2pk(sX[2 * tid], sX[2 * tid + 1]);
      __syncthreads();
      {  // u2 k-chunk-h partial -> disjoint store (h0 adds bias + y1 resid)
        const uint2* wp = (const uint2*)(P.w8 + 7ull * DD * DD) + tid;
        float acc = (h == 0) ? P.ca_bo[tid] + y1s[tid] : 0.f;
        #pragma unroll 8
        for (int j = 0; j < 16; j++) {
          int k4 = h * 16 + j;
          uint2 wv = wp[(size_t)k4 * DD];
          uint2 xv = *(const uint2*)&ph[32 + 2 * j];
          acc = fdot2u(wv.x, xv.x, acc);
          acc = fdot2u(wv.y, xv.y, acc);
        }
        stg_a(&P.u2p[((size_t)b * NH + h) * DD + tid], acc);
      }
    }
    gbar(fl, tid, h, rnd);

    // ==== Phase C: sum u2p -> LN2 -> zs ; FFN1 slice ; fused FFN2 partial ===
    {
      float v = 0.f;
      {
        const float* pp = P.u2p + (size_t)b * NH * DD + tid;
        #pragma unroll
        for (int i = 0; i < 8; i++) v += ldg_a(pp + i * DD);
      }
      {
        int w = tid >> 6, lane = tid & 63;
        float s = v, q2 = v * v;
        #pragma unroll
        for (int m = 32; m >= 1; m >>= 1) { s += __shfl_xor(s, m); q2 += __shfl_xor(q2, m); }
        if (lane == 0) { sAux[w] = s; sAux[8 + w] = q2; }
      }
      __syncthreads();
      {
        float ss = 0.f, qq = 0.f;
        #pragma unroll
        for (int i = 0; i < 8; i++) { ss += sAux[i]; qq += sAux[8 + i]; }
        float mean = ss * (1.f / 512.f);
        float inv = rsqrtf(qq * (1.f / 512.f) - mean * mean + 1e-5f);
        zs[tid] = (v - mean) * inv * P.ln2w[tid] + P.ln2b[tid];
      }
      __syncthreads();
      if (tid < 256) ph[128 + tid] = f2pk(zs[2 * tid], zs[2 * tid + 1]);
      __syncthreads();
      {  // FFN1: cols h*256..h*256+255, k split in 2 halves, dot2
        int c = tid & 255, half = tid >> 8, col = h * 256 + c;
        const uint2* wp = (const uint2*)P.w1b + col;
        float acc = 0.f;
        #pragma unroll 8
        for (int kq = half * 64; kq < half * 64 + 64; kq++) {
          uint2 wv = wp[(size_t)kq * DF];
          uint2 xv = *(const uint2*)&ph[128 + 2 * kq];
          acc = fdot2u(wv.x, xv.x, acc);
          acc = fdot2u(wv.y, xv.y, acc);
        }
        sPart[tid] = acc;
      }
      __syncthreads();
      float* hh = sX;  // relu hidden slice [256]
      if (tid < 256)
        hh[tid] = fmaxf(sPart[tid] + sPart[256 + tid] + P.b1[h * 256 + tid], 0.f);
      __syncthreads();
      if (tid < 128) ph[384 + tid] = f2pk(hh[2 * tid], hh[2 * tid + 1]);
      __syncthreads();
      {  // fused FFN2: u3 partial over k-chunk h (W2 rows h*256..+256), dot2
        const uint2* wp = (const uint2*)P.w2b + tid;
        float acc = (h == 0) ? zs[tid] + P.b2[tid] : 0.f;
        #pragma unroll 8
        for (int j = 0; j < 64; j++) {
          int k4 = h * 64 + j;
          uint2 wv = wp[(size_t)k4 * DD];
          uint2 xv = *(const uint2*)&ph[384 + 2 * j];
          acc = fdot2u(wv.x, xv.x, acc);
          acc = fdot2u(wv.y, xv.y, acc);
        }
        stg_a(&P.u3p[((size_t)b * NH + h) * DD + tid], acc);
      }
    }
    gbar(fl, tid, h, rnd);

    // ==== Phase E: sum u3p -> LN3 ; +ctx(sum) ; xrow=nxt+pe ; h0: out =======
    {
      float u = 0.f, ctxv = 0.f;
      {
        const float* pp = P.u3p + (size_t)b * NH * DD + tid;
        const float* cp = ((t & 1) ? P.ctp1 : P.ctp0) + (size_t)b * NH * DD + tid;
        #pragma unroll
        for (int i = 0; i < 8; i++) { u += ldg_a(pp + i * DD); ctxv += ldg_a(cp + i * DD); }
      }
      {
        int w = tid >> 6, lane = tid & 63;
        float s = u, q2 = u * u;
        #pragma unroll
        for (int m = 32; m >= 1; m >>= 1) { s += __shfl_xor(s, m); q2 += __shfl_xor(q2, m); }
        if (lane == 0) { sAux[w] = s; sAux[8 + w] = q2; }
      }
      __syncthreads();
      float ss = 0.f, qq = 0.f;
      #pragma unroll
      for (int i = 0; i < 8; i++) { ss += sAux[i]; qq += sAux[8 + i]; }
      float mean = ss * (1.f / 512.f);
      float inv = rsqrtf(qq * (1.f / 512.f) - mean * mean + 1e-5f);
      float nxt = (u - mean) * inv * P.ln3w[tid] + P.ln3b[tid] + ctxv;
      float p = (t < TT - 1) ? P.pe[(size_t)(t + 1) * DD + tid] : 0.f;
      if (h == 0) sX[tid] = nxt;
      __syncthreads();
      xrow[tid] = nxt + p;
      if (h == 0) {   // block-uniform branch: inner barrier legal
        {
          int c = tid >> 8, l = tid & 255;
          float a = sX[l] * P.Wout[(size_t)c * DD + l] +
                    sX[l + 256] * P.Wout[(size_t)c * DD + l + 256];
          #pragma unroll
          for (int m = 32; m >= 1; m >>= 1) a += __shfl_xor(a, m);
          if ((tid & 63) == 0) sAux[16 + (tid >> 6)] = a;
        }
        __syncthreads();
        if (tid == 0)
          P.out[((size_t)b * TT + t) * 2 + 0] =
              sAux[16] + sAux[17] + sAux[18] + sAux[19] + P.bout[0];
        if (tid == 256)
          P.out[((size_t)b * TT + t) * 2 + 1] =
              sAux[20] + sAux[21] + sAux[22] + sAux[23] + P.bout[1];
      }
      __syncthreads();
      if (tid < 256) xh[tid] = f2pk(xrow[2 * tid], xrow[2 * tid + 1]);
      __syncthreads();  // xrow/xh stable before next Phase A
    }
    // no barrier: A(t+1) writes only block-private state or the opposite
    // ctx parity buffer; u1p overwrite is >=2 barriers past its readers.
  }
}

// ---- precompute kernels -----------------------------------------------------
__global__ __launch_bounds__(256) void gemm_kv(
    const float* __restrict__ A,
    const float* __restrict__ W0, const float* __restrict__ W1_,
    const float* __restrict__ W2_, const float* __restrict__ W3_,
    const float* __restrict__ b0, const float* __restrict__ b1_,
    const float* __restrict__ b2_, const float* __restrict__ b3_,
    float* __restrict__ O0, float* __restrict__ O1,
    float* __restrict__ O2, float* __restrict__ O3) {
  __shared__ __align__(16) float As[8][128];
  __shared__ __align__(16) float Bs[8][128];
  int tid = threadIdx.x;
  int bx = blockIdx.x, by = blockIdx.y;
  int mm = bx >> 2;
  int col0 = (bx & 3) * 128;
  const float* W = mm == 0 ? W0 : mm == 1 ? W1_ : mm == 2 ? W2_ : W3_;
  const float* bias = mm == 0 ? b0 : mm == 1 ? b1_ : mm == 2 ? b2_ : b3_;
  float* O = mm == 0 ? O0 : mm == 1 ? O1 : mm == 2 ? O2 : O3;
  int tx = tid & 15, ty = tid >> 4;
  int m0 = by * 128;
  int lr = tid >> 1, lk = (tid & 1) * 4;
  const float* Ap = A + (size_t)(m0 + lr) * DD + lk;
  const float* Wp = W + (size_t)(col0 + lr) * DD + lk;
  float c[8][8] = {};
  for (int k0 = 0; k0 < DD; k0 += 8) {
    float4 av = *(const float4*)(Ap + k0);
    float4 wv = *(const float4*)(Wp + k0);
    __syncthreads();
    As[lk + 0][lr] = av.x; As[lk + 1][lr] = av.y; As[lk + 2][lr] = av.z; As[lk + 3][lr] = av.w;
    Bs[lk + 0][lr] = wv.x; Bs[lk + 1][lr] = wv.y; Bs[lk + 2][lr] = wv.z; Bs[lk + 3][lr] = wv.w;
    __syncthreads();
    #pragma unroll
    for (int k = 0; k < 8; k++) {
      float a[8], bb[8];
      *(float4*)&a[0] = *(const float4*)&As[k][ty * 8];
      *(float4*)&a[4] = *(const float4*)&As[k][ty * 8 + 4];
      *(float4*)&bb[0] = *(const float4*)&Bs[k][tx * 8];
      *(float4*)&bb[4] = *(const float4*)&Bs[k][tx * 8 + 4];
      #pragma unroll
      for (int i = 0; i < 8; i++)
        #pragma unroll
        for (int j = 0; j < 8; j++) c[i][j] += a[i] * bb[j];
    }
  }
  const float* bp = bias + col0 + tx * 8;
  for (int i = 0; i < 8; i++) {
    int row = m0 + ty * 8 + i;
    float* op = O + (size_t)row * DD + col0 + tx * 8;
    #pragma unroll
    for (int jq = 0; jq < 8; jq += 4) {
      float4 v;
      v.x = c[i][jq + 0] + bp[jq + 0];
      v.y = c[i][jq + 1] + bp[jq + 1];
      v.z = c[i][jq + 2] + bp[jq + 2];
      v.w = c[i][jq + 3] + bp[jq + 3];
      *(float4*)(op + jq) = v;
    }
  }
}

// K^T packed d-pair layout: uint word w = (d>>1)*NN + n holds f16 elements
// (d, n) in low half (d even) and (d+1, n) in high half.
__global__ __launch_bounds__(256) void pack_kT(const float* __restrict__ Ks32,
                                               const float* __restrict__ Kc32,
                                               ushort_t* __restrict__ KsT,
                                               ushort_t* __restrict__ KcT) {
  int z = blockIdx.z;
  int b = z >> 1;
  const float* in = ((z & 1) ? Kc32 : Ks32) + (size_t)b * NN * DD;
  ushort_t* out = ((z & 1) ? KcT : KsT) + (size_t)b * NN * DD;
  int r0 = blockIdx.x * 32, c0 = blockIdx.y * 32;
  __shared__ float tile[32][33];
  int tid = threadIdx.x;
  int i = tid >> 3, j4 = (tid & 7) * 4;
  float4 v = *(const float4*)(in + (size_t)(r0 + i) * DD + c0 + j4);
  tile[i][j4] = v.x; tile[i][j4 + 1] = v.y; tile[i][j4 + 2] = v.z; tile[i][j4 + 3] = v.w;
  __syncthreads();
  int d = c0 + i;
  ushort_t* op = out + (size_t)(d >> 1) * (2 * NN) + 2 * (r0 + j4) + (d & 1);
  op[0] = f2h(tile[j4][i]);     op[2] = f2h(tile[j4 + 1][i]);
  op[4] = f2h(tile[j4 + 2][i]); op[6] = f2h(tile[j4 + 3][i]);
}

__global__ __launch_bounds__(256) void pack_vh(const float* __restrict__ Vs32,
                                               const float* __restrict__ Vc32,
                                               ushort_t* __restrict__ VsH,
                                               ushort_t* __restrict__ VcH) {
  const float* src = blockIdx.y ? Vc32 : Vs32;
  ushort_t* dst = blockIdx.y ? VcH : VsH;
  size_t idx = (size_t)blockIdx.x * 1024 + threadIdx.x * 4;
  float4 v = *(const float4*)(src + idx);
  int d512 = (int)(idx & 511);
  int n = (int)((idx >> 9) & 255);
  int b = (int)(idx >> 17);
  int h = d512 >> 6, d = d512 & 63;
  ushort_t* op = dst + (((size_t)(b * 8 + h) * NN + n) * DH + d);
  op[0] = f2h(v.x); op[1] = f2h(v.y); op[2] = f2h(v.z); op[3] = f2h(v.w);
}

struct PWItem { const float* in; ushort_t* out; int C; int K; };
struct PWArgs { PWItem m[10]; };
__global__ __launch_bounds__(256) void pack_w(PWArgs a) {
  PWItem it = a.m[blockIdx.y];
  int total = it.C * (it.K >> 2);
  int e = blockIdx.x * 256 + threadIdx.x;
  if (e >= total) return;
  int kd = it.K >> 2;
  int k4 = e % kd, col = e / kd;
  float4 v = *(const float4*)(it.in + (size_t)col * it.K + k4 * 4);
  unsigned lo = f2pk(v.x, v.y), hi = f2pk(v.z, v.w);
  ushort4 o;
  o.x = (ushort_t)(lo & 0xffffu); o.y = (ushort_t)(lo >> 16);
  o.z = (ushort_t)(hi & 0xffffu); o.w = (ushort_t)(hi >> 16);
  *((ushort4*)it.out + (size_t)k4 * it.C + col) = o;
}

__global__ __launch_bounds__(256) void init_x(const float* __restrict__ hv0,
                                              const float* __restrict__ pe,
                                              float* __restrict__ ws,
                                              unsigned* __restrict__ flags) {
  int i = blockIdx.x * 256 + threadIdx.x;
  ws[OFF_X + i] = hv0[i] + pe[i & (DD - 1)];
  if (i < 2048) flags[i] = 0u;
}

// ---------------------------------------------------------------------------
extern "C" void kernel_launch(void* const* d_in, const int* in_sizes, int n_in,
                              void* d_out, int out_size, void* d_ws, size_t ws_size,
                              hipStream_t stream) {
  const float* H_v_all = (const float*)d_in[0];
  const float* H_v0    = (const float*)d_in[1];
  const float* pe      = (const float*)d_in[2];
  const float* s_Wq = (const float*)d_in[3];
  const float* s_Wk = (const float*)d_in[4];
  const float* s_Wv = (const float*)d_in[5];
  const float* s_Wo = (const float*)d_in[6];
  const float* s_bq = (const float*)d_in[7];
  const float* s_bk = (const float*)d_in[8];
  const float* s_bv = (const float*)d_in[9];
  const float* s_bo = (const float*)d_in[10];
  const float* sa_Wq = (const float*)d_in[11];
  const float* sa_Wk = (const float*)d_in[12];
  const float* sa_Wv = (const float*)d_in[13];
  const float* sa_Wo = (const float*)d_in[14];
  const float* sa_bq = (const float*)d_in[15];
  const float* sa_bk = (const float*)d_in[16];
  const float* sa_bv = (const float*)d_in[17];
  const float* sa_bo = (const float*)d_in[18];
  const float* ca_Wq = (const float*)d_in[19];
  const float* ca_Wk = (const float*)d_in[20];
  const float* ca_Wv = (const float*)d_in[21];
  const float* ca_Wo = (const float*)d_in[22];
  const float* ca_bq = (const float*)d_in[23];
  const float* ca_bk = (const float*)d_in[24];
  const float* ca_bv = (const float*)d_in[25];
  const float* ca_bo = (const float*)d_in[26];
  const float* ln1w = (const float*)d_in[27];
  const float* ln1b = (const float*)d_in[28];
  const float* ln2w = (const float*)d_in[29];
  const float* ln2b = (const float*)d_in[30];
  const float* ln3w = (const float*)d_in[31];
  const float* ln3b = (const float*)d_in[32];
  const float* W1   = (const float*)d_in[33];
  const float* b1   = (const float*)d_in[34];
  const float* W2   = (const float*)d_in[35];
  const float* b2   = (const float*)d_in[36];
  const float* Wout = (const float*)d_in[37];
  const float* bout = (const float*)d_in[38];

  float* ws = (float*)d_ws;
  float* Ks32 = ws + OFF_KS32;
  float* Vs32 = ws + OFF_VS32;
  float* Kc32 = ws + OFF_KC32;
  float* Vc32 = ws + OFF_VC32;
  ushort_t* ub = (ushort_t*)(ws + OFF_BF);
  unsigned* flags = (unsigned*)(ws + OFF_FLG);

  hipLaunchKernelGGL(gemm_kv, dim3(16, 64), dim3(256), 0, stream,
                     H_v_all, s_Wk, s_Wv, ca_Wk, ca_Wv,
                     s_bk, s_bv, ca_bk, ca_bv, Ks32, Vs32, Kc32, Vc32);

  hipLaunchKernelGGL(pack_kT, dim3(8, 16, 64), dim3(256), 0, stream,
                     Ks32, Kc32, ub + UOFF_KST, ub + UOFF_KCT);
  hipLaunchKernelGGL(pack_vh, dim3((unsigned)(SZ_KV / 1024), 2), dim3(256), 0,
                     stream, Vs32, Vc32, ub + UOFF_VSH, ub + UOFF_VCH);

  PWArgs pw;
  pw.m[0] = {sa_Wq, ub + UOFF_W8 + 0ull * DD * DD, DD, DD};
  pw.m[1] = {sa_Wk, ub + UOFF_W8 + 1ull * DD * DD, DD, DD};
  pw.m[2] = {sa_Wv, ub + UOFF_W8 + 2ull * DD * DD, DD, DD};
  pw.m[3] = {s_Wq,  ub + UOFF_W8 + 3ull * DD * DD, DD, DD};
  pw.m[4] = {sa_Wo, ub + UOFF_W8 + 4ull * DD * DD, DD, DD};
  pw.m[5] = {s_Wo,  ub + UOFF_W8 + 5ull * DD * DD, DD, DD};
  pw.m[6] = {ca_Wq, ub + UOFF_W8 + 6ull * DD * DD, DD, DD};
  pw.m[7] = {ca_Wo, ub + UOFF_W8 + 7ull * DD * DD, DD, DD};
  pw.m[8] = {W1, ub + UOFF_W1, DF, DD};
  pw.m[9] = {W2, ub + UOFF_W2, DD, DF};
  hipLaunchKernelGGL(pack_w, dim3(1024, 10), dim3(256), 0, stream, pw);

  hipLaunchKernelGGL(init_x, dim3(64), dim3(256), 0, stream,
                     H_v0, pe, ws, flags);

  // Raise dynamic-LDS cap (host-side attribute set; idempotent; not a
  // stream op so safe under graph capture).
  static bool attr_set = false;
  if (!attr_set) {
    hipFuncSetAttribute((const void*)decode_persistent,
                        hipFuncAttributeMaxDynamicSharedMemorySize, DYN_LDS);
    attr_set = true;
  }

  Params P;
  P.pe = pe;
  P.sa_bq = sa_bq; P.sa_bk = sa_bk; P.sa_bv = sa_bv; P.s_bq = s_bq;
  P.sa_bo = sa_bo; P.s_bo = s_bo; P.ca_bq = ca_bq; P.ca_bo = ca_bo;
  P.ln1w = ln1w; P.ln1b = ln1b; P.ln2w = ln2w; P.ln2b = ln2b;
  P.ln3w = ln3w; P.ln3b = ln3b;
  P.b1 = b1; P.b2 = b2; P.Wout = Wout; P.bout = bout;
  P.w8 = ub + UOFF_W8; P.w1b = ub + UOFF_W1; P.w2b = ub + UOFF_W2;
  P.KsT = ub + UOFF_KST; P.KcT = ub + UOFF_KCT;
  P.VsH = ub + UOFF_VSH; P.VcH = ub + UOFF_VCH;
  P.KsaB = ub + UOFF_KSA; P.VsaB = ub + UOFF_VSA;
  P.xcur = ws + OFF_X;
  P.u1p = ws + OFF_U1P; P.u2p = ws + OFF_U2P; P.u3p = ws + OFF_U3P;
  P.ctp0 = ws + OFF_CTP0; P.ctp1 = ws + OFF_CTP1;
  P.out = (float*)d_out;
  P.flags = flags;

  void* kargs[] = { (void*)&P };
  hipLaunchCooperativeKernel((void*)decode_persistent, dim3(NBLK), dim3(NTHR),
                             kargs, DYN_LDS, stream);
}